// Round 1
// baseline (2243.959 us; speedup 1.0000x reference)
//
#include <hip/hip_runtime.h>
#include <cstdint>
#include <cstddef>

#define NN 262144
#define EE 2097152
#define BB 64
#define CCROSS 32
#define PCC 128
#define PP 2048

static __device__ __forceinline__ float lrelu(float x, float s) { return x > 0.f ? x : s * x; }

// ---------------- CSR build ----------------
__global__ void hist_k(const int* __restrict__ dst, int* __restrict__ cnt) {
    int e = blockIdx.x * 256 + threadIdx.x;
    if (e >= EE) return;
    atomicAdd(&cnt[dst[e]], 1);
}

__global__ void dinv_k(const int* __restrict__ cnt, float* __restrict__ dinv) {
    int v = blockIdx.x * 256 + threadIdx.x;
    if (v >= NN) return;
    dinv[v] = rsqrtf((float)(cnt[v] + 1));
}

__global__ void scan_block_k(const int* __restrict__ in, int* __restrict__ out, int* __restrict__ bsum) {
    __shared__ int tmp[1024];
    int tid = threadIdx.x;
    int gid = blockIdx.x * 1024 + tid;
    int v = in[gid];
    tmp[tid] = v;
    __syncthreads();
    for (int off = 1; off < 1024; off <<= 1) {
        int t = (tid >= off) ? tmp[tid - off] : 0;
        __syncthreads();
        tmp[tid] += t;
        __syncthreads();
    }
    out[gid] = tmp[tid] - v;  // exclusive
    if (tid == 1023) bsum[blockIdx.x] = tmp[tid];
}

__global__ void scan_top_k(const int* __restrict__ bsum, int* __restrict__ boff) {
    __shared__ int tmp[256];
    int tid = threadIdx.x;
    int v = bsum[tid];
    tmp[tid] = v;
    __syncthreads();
    for (int off = 1; off < 256; off <<= 1) {
        int t = (tid >= off) ? tmp[tid - off] : 0;
        __syncthreads();
        tmp[tid] += t;
        __syncthreads();
    }
    boff[tid] = tmp[tid] - v;
}

__global__ void add_off_k(int* __restrict__ rp, const int* __restrict__ boff) {
    int gid = blockIdx.x * 1024 + threadIdx.x;
    rp[gid] += boff[blockIdx.x];
    if (gid == 0) rp[NN] = EE;
}

__global__ void scatter_k(const int* __restrict__ src, const int* __restrict__ dst,
                          const int* __restrict__ rp, int* __restrict__ fill, int* __restrict__ col) {
    int e = blockIdx.x * 256 + threadIdx.x;
    if (e >= EE) return;
    int d = dst[e];
    int pos = rp[d] + atomicAdd(&fill[d], 1);
    col[pos] = src[e];
}

// ---------------- skinny GEMM:  y[v] = (x[v] @ W) [* dinv[v]]  (+ es/ed dots) ----------------
template <int KIN, int KOUT, bool SCALE, bool ESED>
__global__ void gemm_k(const float* __restrict__ x, const float* __restrict__ W,
                       const float* __restrict__ dinv, float* __restrict__ y,
                       const float* __restrict__ av, const float* __restrict__ ad,
                       float* __restrict__ es, float* __restrict__ ed, int n) {
    int v = blockIdx.x * 256 + threadIdx.x;
    if (v >= n) return;
    const float* xr = x + (size_t)v * KIN;
    float acc[KOUT];
#pragma unroll
    for (int j = 0; j < KOUT; j++) acc[j] = 0.f;
#pragma unroll 2
    for (int k = 0; k < KIN; k++) {
        float xv = xr[k];
#pragma unroll
        for (int j = 0; j < KOUT; j++) acc[j] = fmaf(xv, W[k * KOUT + j], acc[j]);
    }
    float s = 1.f;
    if constexpr (SCALE) s = dinv[v];
    float e1 = 0.f, e2 = 0.f;
    float4* y4 = (float4*)(y + (size_t)v * KOUT);
#pragma unroll
    for (int j4 = 0; j4 < KOUT / 4; j4++) {
        float4 t;
        t.x = acc[4 * j4 + 0] * s;
        t.y = acc[4 * j4 + 1] * s;
        t.z = acc[4 * j4 + 2] * s;
        t.w = acc[4 * j4 + 3] * s;
        y4[j4] = t;
        if constexpr (ESED) {
            e1 = fmaf(t.x, av[4 * j4 + 0], e1); e1 = fmaf(t.y, av[4 * j4 + 1], e1);
            e1 = fmaf(t.z, av[4 * j4 + 2], e1); e1 = fmaf(t.w, av[4 * j4 + 3], e1);
            e2 = fmaf(t.x, ad[4 * j4 + 0], e2); e2 = fmaf(t.y, ad[4 * j4 + 1], e2);
            e2 = fmaf(t.z, ad[4 * j4 + 2], e2); e2 = fmaf(t.w, ad[4 * j4 + 3], e2);
        }
    }
    if constexpr (ESED) { es[v] = e1; ed[v] = e2; }
}

// ---------------- GCN aggregation:  out[v] = act(dinv[v]*(y[v] + sum_in y[s]) + b) ----------------
template <int F, int ACT>  // ACT: 0 relu, 1 leaky 0.01
__global__ void gcn_agg_k(const float* __restrict__ y, const int* __restrict__ rp,
                          const int* __restrict__ col, const float* __restrict__ dinv,
                          const float* __restrict__ bias, float* __restrict__ out) {
    int gid = blockIdx.x * 256 + threadIdx.x;
    if (gid >= NN * F) return;
    int v = gid / F;
    int f = gid - v * F;
    float acc = y[gid];  // self loop (y already pre-scaled by dinv)
    int s = rp[v], e = rp[v + 1];
    for (int i = s; i < e; i++) {
        int u = col[i];
        acc += y[(size_t)u * F + f];
    }
    acc = acc * dinv[v] + bias[f];
    out[gid] = (ACT == 0) ? fmaxf(acc, 0.f) : lrelu(acc, 0.01f);
}

// ---------------- GAT edge softmax weights (per dst node) ----------------
__global__ void gat_w_k(const float* __restrict__ es, const float* __restrict__ ed,
                        const int* __restrict__ rp, const int* __restrict__ col,
                        float* __restrict__ ew, float* __restrict__ wself, float* __restrict__ invden) {
    int v = blockIdx.x * 256 + threadIdx.x;
    if (v >= NN) return;
    float edv = ed[v];
    float eself = lrelu(es[v] + edv, 0.2f);
    float m = eself;
    int s = rp[v], e = rp[v + 1];
    for (int i = s; i < e; i++) {
        float t = lrelu(es[col[i]] + edv, 0.2f);
        m = fmaxf(m, t);
    }
    float wsl = __expf(eself - m);
    float den = wsl;
    for (int i = s; i < e; i++) {
        float t = lrelu(es[col[i]] + edv, 0.2f);
        float w = __expf(t - m);
        ew[i] = w;
        den += w;
    }
    wself[v] = wsl;
    invden[v] = 1.f / den;
}

__global__ void gat_agg_k(const float* __restrict__ y, const int* __restrict__ rp,
                          const int* __restrict__ col, const float* __restrict__ ew,
                          const float* __restrict__ wself, const float* __restrict__ invden,
                          const float* __restrict__ bias, float* __restrict__ out) {
    int gid = blockIdx.x * 256 + threadIdx.x;
    if (gid >= NN * 64) return;
    int v = gid >> 6, f = gid & 63;
    float acc = wself[v] * y[gid];
    int s = rp[v], e = rp[v + 1];
    for (int i = s; i < e; i++) acc = fmaf(ew[i], y[(size_t)col[i] * 64 + f], acc);
    out[gid] = acc * invden[v] + bias[f];
}

// ---------------- pooling ----------------
__global__ void pool_pieces_k(const float* __restrict__ in, float* __restrict__ out) {
    int gid = blockIdx.x * 256 + threadIdx.x;  // 2048*64
    if (gid >= BB * CCROSS * 64) return;
    int f = gid & 63, g = gid >> 6;
    const float* p = in + (size_t)g * PCC * 64 + f;
    float s = 0.f;
#pragma unroll 8
    for (int i = 0; i < PCC; i++) s += p[(size_t)i * 64];
    out[gid] = s * (1.f / 128.f);
}

__global__ void pool_cross_k(const float* __restrict__ in, float* __restrict__ out) {
    int gid = blockIdx.x * 64 + threadIdx.x;  // 64*64
    if (gid >= BB * 64) return;
    int f = gid & 63, b = gid >> 6;
    const float* p = in + (size_t)b * CCROSS * 64 + f;
    float s = 0.f;
#pragma unroll
    for (int i = 0; i < CCROSS; i++) s += p[(size_t)i * 64];
    out[gid] = s * (1.f / 32.f);
}

__global__ void pool_points_k(const float* __restrict__ in, float* __restrict__ out) {
    int gid = blockIdx.x * 256 + threadIdx.x;  // 64*64 (b,o)
    if (gid >= BB * 64) return;
    const float* p = in + (size_t)gid * 256;
    float s = 0.f;
    for (int t = 0; t < 256; t++) s += p[t];
    out[gid] = s * (1.f / 256.f);
}

// ---------------- dense cross-graph GAT (32 nodes/graph, multiplicity 2 off-diagonal) ----------------
__global__ void cross_att_k(const float* __restrict__ xw, const float* __restrict__ es,
                            const float* __restrict__ ed, const float* __restrict__ bg,
                            float* __restrict__ out) {
    int gid = blockIdx.x * 256 + threadIdx.x;  // 64*32*64
    if (gid >= BB * CCROSS * 64) return;
    int f = gid & 63;
    int d = (gid >> 6) & 31;
    int g = gid >> 11;
    int base = g * CCROSS;
    float edd = ed[base + d];
    float m = -1e30f;
#pragma unroll
    for (int s = 0; s < CCROSS; s++) {
        float e = lrelu(es[base + s] + edd, 0.2f);
        m = fmaxf(m, e);
    }
    float den = 0.f, acc = 0.f;
#pragma unroll
    for (int s = 0; s < CCROSS; s++) {
        float e = lrelu(es[base + s] + edd, 0.2f);
        float w = __expf(e - m) * ((s == d) ? 1.f : 2.f);
        den += w;
        acc = fmaf(w, xw[(size_t)(base + s) * 64 + f], acc);
    }
    out[gid] = acc / den + bg[f];
}

// ---------------- conv1d stride 2 pad 1 k=3, leaky 0.01, optional eval-BN ----------------
template <int CIN, int COUT, int LIN, bool BN>
__global__ void conv_k(const float* __restrict__ in, const float* __restrict__ W,
                       const float* __restrict__ bias, const float* __restrict__ g,
                       const float* __restrict__ be, float* __restrict__ out) {
    constexpr int LOUT = LIN / 2;
    int gid = blockIdx.x * 256 + threadIdx.x;
    if (gid >= BB * COUT * LOUT) return;
    int t = gid % LOUT;
    int o = (gid / LOUT) % COUT;
    int b = gid / (LOUT * COUT);
    const float* inb = in + (size_t)b * CIN * LIN;
    const float* wo = W + (size_t)o * CIN * 3;
    float acc = bias[o];
    int p0 = 2 * t - 1;
#pragma unroll
    for (int i = 0; i < CIN; i++) {
        const float* row = inb + (size_t)i * LIN;
        float w0 = wo[i * 3 + 0], w1 = wo[i * 3 + 1], w2 = wo[i * 3 + 2];
        float x0 = (p0 >= 0) ? row[p0] : 0.f;
        float x1 = row[p0 + 1];
        float x2 = (p0 + 2 < LIN) ? row[p0 + 2] : 0.f;
        acc = fmaf(x0, w0, acc);
        acc = fmaf(x1, w1, acc);
        acc = fmaf(x2, w2, acc);
    }
    acc = lrelu(acc, 0.01f);
    if constexpr (BN) acc = fmaf(acc, g[o] * 0.99999500003749968f, be[o]);
    out[gid] = acc;
}

// ---------------- head:  out = sigmoid(leaky(h@Wl2+bl2)@Wl3 + bl3) ----------------
__global__ void head_k(const float* __restrict__ hG, const float* __restrict__ pvec,
                       const float* __restrict__ Wl2, const float* __restrict__ bl2,
                       const float* __restrict__ Wl3, const float* __restrict__ bl3,
                       float* __restrict__ out) {
    int b = blockIdx.x;
    int f = threadIdx.x;  // 64
    __shared__ float sh[64];
    float h = hG[b * 64 + f] + pvec[b * 64 + f];
    sh[f] = h;
    __syncthreads();
    float acc = bl2[f];
#pragma unroll
    for (int k = 0; k < 64; k++) acc = fmaf(sh[k], Wl2[k * 64 + f], acc);
    acc = lrelu(acc, 0.01f);
    float pr = acc * Wl3[f];
#pragma unroll
    for (int off = 32; off > 0; off >>= 1) pr += __shfl_down(pr, off, 64);
    if (f == 0) out[b] = 1.f / (1.f + __expf(-(pr + bl3[0])));
}

extern "C" void kernel_launch(void* const* d_in, const int* in_sizes, int n_in,
                              void* d_out, int out_size, void* d_ws, size_t ws_size,
                              hipStream_t stream) {
    const float* x = (const float*)d_in[0];
    const int* ei = (const int*)d_in[1];
    const float* points = (const float*)d_in[2];
    const float* W1 = (const float*)d_in[3];
    const float* b1 = (const float*)d_in[4];
    const float* W2 = (const float*)d_in[5];
    const float* b2 = (const float*)d_in[6];
    const float* W3 = (const float*)d_in[7];
    const float* b3 = (const float*)d_in[8];
    const float* Wg1 = (const float*)d_in[9];
    const float* asrc1 = (const float*)d_in[10];
    const float* adst1 = (const float*)d_in[11];
    const float* bg1 = (const float*)d_in[12];
    const float* Wg2 = (const float*)d_in[13];
    const float* asrc2 = (const float*)d_in[14];
    const float* adst2 = (const float*)d_in[15];
    const float* bg2 = (const float*)d_in[16];
    const float* c1W = (const float*)d_in[17];
    const float* c1b = (const float*)d_in[18];
    const float* g1 = (const float*)d_in[19];
    const float* be1 = (const float*)d_in[20];
    const float* c2W = (const float*)d_in[21];
    const float* c2b = (const float*)d_in[22];
    const float* g2 = (const float*)d_in[23];
    const float* be2 = (const float*)d_in[24];
    const float* c3W = (const float*)d_in[25];
    const float* c3b = (const float*)d_in[26];
    const float* Wl2 = (const float*)d_in[27];
    const float* bl2 = (const float*)d_in[28];
    const float* Wl3 = (const float*)d_in[29];
    const float* bl3 = (const float*)d_in[30];

    const int* src = ei;
    const int* dst = ei + EE;

    // ---- workspace carve-up ----
    char* w = (char*)d_ws;
    size_t off = 0;
    auto A = [&](size_t bytes) -> void* {
        void* p = w + off;
        off = (off + bytes + 255) & ~(size_t)255;
        return p;
    };
    int* colb = (int*)A((size_t)EE * 4);
    int* rp = (int*)A((size_t)(NN + 1) * 4);
    int* cnt = (int*)A((size_t)NN * 4);
    int* bsum = (int*)A(256 * 4);
    int* boff = (int*)A(256 * 4);
    float* dinv = (float*)A((size_t)NN * 4);
    float* bufA = (float*)A((size_t)NN * 64 * 4);
    float* bufB = (float*)A((size_t)NN * 64 * 4);
    float* ew = (float*)A((size_t)EE * 4);
    float* wself = (float*)A((size_t)NN * 4);
    float* invden = (float*)A((size_t)NN * 4);
    float* es = (float*)A((size_t)NN * 4);
    float* edv = (float*)A((size_t)NN * 4);
    float* pooled = (float*)A((size_t)BB * CCROSS * 64 * 4);
    float* xw2 = (float*)A((size_t)BB * CCROSS * 64 * 4);
    float* es2 = (float*)A((size_t)BB * CCROSS * 4);
    float* ed2 = (float*)A((size_t)BB * CCROSS * 4);
    float* crosso = (float*)A((size_t)BB * CCROSS * 64 * 4);
    float* hG = (float*)A((size_t)BB * 64 * 4);
    float* pvec = (float*)A((size_t)BB * 64 * 4);

    // ---- CSR build (dst-sorted) + dinv ----
    hipMemsetAsync(cnt, 0, (size_t)NN * 4, stream);
    hist_k<<<EE / 256, 256, 0, stream>>>(dst, cnt);
    dinv_k<<<NN / 256, 256, 0, stream>>>(cnt, dinv);
    scan_block_k<<<256, 1024, 0, stream>>>(cnt, rp, bsum);
    scan_top_k<<<1, 256, 0, stream>>>(bsum, boff);
    add_off_k<<<256, 1024, 0, stream>>>(rp, boff);
    hipMemsetAsync(cnt, 0, (size_t)NN * 4, stream);
    scatter_k<<<EE / 256, 256, 0, stream>>>(src, dst, rp, cnt, colb);

    // ---- GCN 1/2/3 ----
    gemm_k<19, 32, true, false><<<NN / 256, 256, 0, stream>>>(x, W1, dinv, bufA, nullptr, nullptr, nullptr, nullptr, NN);
    gcn_agg_k<32, 0><<<(NN * 32) / 256, 256, 0, stream>>>(bufA, rp, colb, dinv, b1, bufB);
    gemm_k<32, 64, true, false><<<NN / 256, 256, 0, stream>>>(bufB, W2, dinv, bufA, nullptr, nullptr, nullptr, nullptr, NN);
    gcn_agg_k<64, 1><<<(NN * 64) / 256, 256, 0, stream>>>(bufA, rp, colb, dinv, b2, bufB);
    gemm_k<64, 64, true, false><<<NN / 256, 256, 0, stream>>>(bufB, W3, dinv, bufA, nullptr, nullptr, nullptr, nullptr, NN);
    gcn_agg_k<64, 1><<<(NN * 64) / 256, 256, 0, stream>>>(bufA, rp, colb, dinv, b3, bufB);

    // ---- GAT 1 ----
    gemm_k<64, 64, false, true><<<NN / 256, 256, 0, stream>>>(bufB, Wg1, nullptr, bufA, asrc1, adst1, es, edv, NN);
    gat_w_k<<<NN / 256, 256, 0, stream>>>(es, edv, rp, colb, ew, wself, invden);
    gat_agg_k<<<(NN * 64) / 256, 256, 0, stream>>>(bufA, rp, colb, ew, wself, invden, bg1, bufB);

    // ---- pool pieces -> cross GAT -> pool cross ----
    pool_pieces_k<<<(BB * CCROSS * 64) / 256, 256, 0, stream>>>(bufB, pooled);
    gemm_k<64, 64, false, true><<<(BB * CCROSS) / 256, 256, 0, stream>>>(pooled, Wg2, nullptr, xw2, asrc2, adst2, es2, ed2, BB * CCROSS);
    cross_att_k<<<(BB * CCROSS * 64) / 256, 256, 0, stream>>>(xw2, es2, ed2, bg2, crosso);
    pool_cross_k<<<BB, 64, 0, stream>>>(crosso, hG);

    // ---- points branch (reuses bufA/bufB, graph branch is done with them) ----
    conv_k<3, 32, 2048, true><<<(BB * 32 * 1024) / 256, 256, 0, stream>>>(points, c1W, c1b, g1, be1, bufA);
    conv_k<32, 64, 1024, true><<<(BB * 64 * 512) / 256, 256, 0, stream>>>(bufA, c2W, c2b, g2, be2, bufB);
    conv_k<64, 64, 512, false><<<(BB * 64 * 256) / 256, 256, 0, stream>>>(bufB, c3W, c3b, nullptr, nullptr, bufA);
    pool_points_k<<<(BB * 64 + 255) / 256, 256, 0, stream>>>(bufA, pvec);

    // ---- head ----
    head_k<<<BB, 64, 0, stream>>>(hG, pvec, Wl2, bl2, Wl3, bl3, (float*)d_out);
}

// Round 2
// 1430.809 us; speedup vs baseline: 1.5683x; 1.5683x over previous
//
#include <hip/hip_runtime.h>
#include <cstdint>
#include <cstddef>

#define NN 262144
#define EE 2097152
#define BB 64
#define CCROSS 32
#define PCC 128
#define PP 2048

static __device__ __forceinline__ float lrelu(float x, float s) { return x > 0.f ? x : s * x; }

// ---------------- CSR build ----------------
__global__ void hist_k(const int* __restrict__ dst, int* __restrict__ cnt) {
    int e = blockIdx.x * 256 + threadIdx.x;
    if (e >= EE) return;
    atomicAdd(&cnt[dst[e]], 1);
}

__global__ void dinv_k(const int* __restrict__ cnt, float* __restrict__ dinv) {
    int v = blockIdx.x * 256 + threadIdx.x;
    if (v >= NN) return;
    dinv[v] = rsqrtf((float)(cnt[v] + 1));
}

__global__ void scan_block_k(const int* __restrict__ in, int* __restrict__ out, int* __restrict__ bsum) {
    __shared__ int tmp[1024];
    int tid = threadIdx.x;
    int gid = blockIdx.x * 1024 + tid;
    int v = in[gid];
    tmp[tid] = v;
    __syncthreads();
    for (int off = 1; off < 1024; off <<= 1) {
        int t = (tid >= off) ? tmp[tid - off] : 0;
        __syncthreads();
        tmp[tid] += t;
        __syncthreads();
    }
    out[gid] = tmp[tid] - v;  // exclusive
    if (tid == 1023) bsum[blockIdx.x] = tmp[tid];
}

__global__ void scan_top_k(const int* __restrict__ bsum, int* __restrict__ boff) {
    __shared__ int tmp[256];
    int tid = threadIdx.x;
    int v = bsum[tid];
    tmp[tid] = v;
    __syncthreads();
    for (int off = 1; off < 256; off <<= 1) {
        int t = (tid >= off) ? tmp[tid - off] : 0;
        __syncthreads();
        tmp[tid] += t;
        __syncthreads();
    }
    boff[tid] = tmp[tid] - v;
}

__global__ void add_off_k(int* __restrict__ rp, const int* __restrict__ boff) {
    int gid = blockIdx.x * 1024 + threadIdx.x;
    rp[gid] += boff[blockIdx.x];
    if (gid == 0) rp[NN] = EE;
}

__global__ void scatter_k(const int* __restrict__ src, const int* __restrict__ dst,
                          const int* __restrict__ rp, int* __restrict__ fill, int* __restrict__ col) {
    int e = blockIdx.x * 256 + threadIdx.x;
    if (e >= EE) return;
    int d = dst[e];
    int pos = rp[d] + atomicAdd(&fill[d], 1);
    col[pos] = src[e];
}

// ---------------- skinny GEMM:  y[v] = (x[v] @ W) [* dinv[v]]  (+ es/ed dots) ----------------
template <int KIN, int KOUT, bool SCALE, bool ESED>
__global__ void gemm_k(const float* __restrict__ x, const float* __restrict__ W,
                       const float* __restrict__ dinv, float* __restrict__ y,
                       const float* __restrict__ av, const float* __restrict__ ad,
                       float* __restrict__ es, float* __restrict__ ed, int n) {
    int v = blockIdx.x * 256 + threadIdx.x;
    if (v >= n) return;
    const float* xr = x + (size_t)v * KIN;
    float acc[KOUT];
#pragma unroll
    for (int j = 0; j < KOUT; j++) acc[j] = 0.f;
#pragma unroll 2
    for (int k = 0; k < KIN; k++) {
        float xv = xr[k];
#pragma unroll
        for (int j = 0; j < KOUT; j++) acc[j] = fmaf(xv, W[k * KOUT + j], acc[j]);
    }
    float s = 1.f;
    if constexpr (SCALE) s = dinv[v];
    float e1 = 0.f, e2 = 0.f;
    float4* y4 = (float4*)(y + (size_t)v * KOUT);
#pragma unroll
    for (int j4 = 0; j4 < KOUT / 4; j4++) {
        float4 t;
        t.x = acc[4 * j4 + 0] * s;
        t.y = acc[4 * j4 + 1] * s;
        t.z = acc[4 * j4 + 2] * s;
        t.w = acc[4 * j4 + 3] * s;
        y4[j4] = t;
        if constexpr (ESED) {
            e1 = fmaf(t.x, av[4 * j4 + 0], e1); e1 = fmaf(t.y, av[4 * j4 + 1], e1);
            e1 = fmaf(t.z, av[4 * j4 + 2], e1); e1 = fmaf(t.w, av[4 * j4 + 3], e1);
            e2 = fmaf(t.x, ad[4 * j4 + 0], e2); e2 = fmaf(t.y, ad[4 * j4 + 1], e2);
            e2 = fmaf(t.z, ad[4 * j4 + 2], e2); e2 = fmaf(t.w, ad[4 * j4 + 3], e2);
        }
    }
    if constexpr (ESED) { es[v] = e1; ed[v] = e2; }
}

// ---------------- GCN aggregation:  out[v] = act(dinv[v]*(y[v] + sum_in y[s]) + b) ----------------
template <int F, int ACT>  // ACT: 0 relu, 1 leaky 0.01
__global__ void gcn_agg_k(const float* __restrict__ y, const int* __restrict__ rp,
                          const int* __restrict__ col, const float* __restrict__ dinv,
                          const float* __restrict__ bias, float* __restrict__ out) {
    int gid = blockIdx.x * 256 + threadIdx.x;
    if (gid >= NN * F) return;
    int v = gid / F;
    int f = gid - v * F;
    float acc = y[gid];  // self loop (y already pre-scaled by dinv)
    int s = rp[v], e = rp[v + 1];
    for (int i = s; i < e; i++) {
        int u = col[i];
        acc += y[(size_t)u * F + f];
    }
    acc = acc * dinv[v] + bias[f];
    out[gid] = (ACT == 0) ? fmaxf(acc, 0.f) : lrelu(acc, 0.01f);
}

// ---------------- GAT edge softmax weights (per dst node) ----------------
__global__ void gat_w_k(const float* __restrict__ es, const float* __restrict__ ed,
                        const int* __restrict__ rp, const int* __restrict__ col,
                        float* __restrict__ ew, float* __restrict__ wself, float* __restrict__ invden) {
    int v = blockIdx.x * 256 + threadIdx.x;
    if (v >= NN) return;
    float edv = ed[v];
    float eself = lrelu(es[v] + edv, 0.2f);
    float m = eself;
    int s = rp[v], e = rp[v + 1];
    for (int i = s; i < e; i++) {
        float t = lrelu(es[col[i]] + edv, 0.2f);
        m = fmaxf(m, t);
    }
    float wsl = __expf(eself - m);
    float den = wsl;
    for (int i = s; i < e; i++) {
        float t = lrelu(es[col[i]] + edv, 0.2f);
        float w = __expf(t - m);
        ew[i] = w;
        den += w;
    }
    wself[v] = wsl;
    invden[v] = 1.f / den;
}

__global__ void gat_agg_k(const float* __restrict__ y, const int* __restrict__ rp,
                          const int* __restrict__ col, const float* __restrict__ ew,
                          const float* __restrict__ wself, const float* __restrict__ invden,
                          const float* __restrict__ bias, float* __restrict__ out) {
    int gid = blockIdx.x * 256 + threadIdx.x;
    if (gid >= NN * 64) return;
    int v = gid >> 6, f = gid & 63;
    float acc = wself[v] * y[gid];
    int s = rp[v], e = rp[v + 1];
    for (int i = s; i < e; i++) acc = fmaf(ew[i], y[(size_t)col[i] * 64 + f], acc);
    out[gid] = acc * invden[v] + bias[f];
}

// ---------------- pooling ----------------
__global__ void pool_pieces_k(const float* __restrict__ in, float* __restrict__ out) {
    int gid = blockIdx.x * 256 + threadIdx.x;  // 2048*64
    if (gid >= BB * CCROSS * 64) return;
    int f = gid & 63, g = gid >> 6;
    const float* p = in + (size_t)g * PCC * 64 + f;
    float s = 0.f;
#pragma unroll 8
    for (int i = 0; i < PCC; i++) s += p[(size_t)i * 64];
    out[gid] = s * (1.f / 128.f);
}

__global__ void pool_cross_k(const float* __restrict__ in, float* __restrict__ out) {
    int gid = blockIdx.x * 64 + threadIdx.x;  // 64*64
    if (gid >= BB * 64) return;
    int f = gid & 63, b = gid >> 6;
    const float* p = in + (size_t)b * CCROSS * 64 + f;
    float s = 0.f;
#pragma unroll
    for (int i = 0; i < CCROSS; i++) s += p[(size_t)i * 64];
    out[gid] = s * (1.f / 32.f);
}

// ---------------- dense cross-graph GAT (32 nodes/graph, multiplicity 2 off-diagonal) ----------------
__global__ void cross_att_k(const float* __restrict__ xw, const float* __restrict__ es,
                            const float* __restrict__ ed, const float* __restrict__ bg,
                            float* __restrict__ out) {
    int gid = blockIdx.x * 256 + threadIdx.x;  // 64*32*64
    if (gid >= BB * CCROSS * 64) return;
    int f = gid & 63;
    int d = (gid >> 6) & 31;
    int g = gid >> 11;
    int base = g * CCROSS;
    float edd = ed[base + d];
    float m = -1e30f;
#pragma unroll
    for (int s = 0; s < CCROSS; s++) {
        float e = lrelu(es[base + s] + edd, 0.2f);
        m = fmaxf(m, e);
    }
    float den = 0.f, acc = 0.f;
#pragma unroll
    for (int s = 0; s < CCROSS; s++) {
        float e = lrelu(es[base + s] + edd, 0.2f);
        float w = __expf(e - m) * ((s == d) ? 1.f : 2.f);
        den += w;
        acc = fmaf(w, xw[(size_t)(base + s) * 64 + f], acc);
    }
    out[gid] = acc / den + bg[f];
}

// ---------------- fused conv1->conv2->conv3->avgpool, per (batch, 32-wide conv3 tile) ----------------
// q in [0,8): conv3 out positions t3 in [32q, 32q+32)
// needs conv2-out p2 in [64q-1, 64q+64)   (65)
// needs conv1-out p1 in [128q-3, 128q+128) (131)
// needs points  p0 in [256q-7, 256q+256) (263)
// LDS: s0[3][264] + s1[32][132] + s2[64][66]; s3[64*32] aliases s0/s1.
#define S0_STR 264
#define S1_STR 132
#define S2_STR 66
#define S0_OFF 0
#define S1_OFF (3 * S0_STR)
#define S2_OFF (S1_OFF + 32 * S1_STR)
#define SMEM_FLOATS (S2_OFF + 64 * S2_STR)

__global__ __launch_bounds__(256) void conv_fused_k(
        const float* __restrict__ pts, const float* __restrict__ c1W, const float* __restrict__ c1b,
        const float* __restrict__ g1, const float* __restrict__ be1,
        const float* __restrict__ c2W, const float* __restrict__ c2b,
        const float* __restrict__ g2, const float* __restrict__ be2,
        const float* __restrict__ c3W, const float* __restrict__ c3b,
        float* __restrict__ partials /* [BB][8][64] */) {
    __shared__ float smem[SMEM_FLOATS];
    float* s0 = smem + S0_OFF;
    float* s1 = smem + S1_OFF;
    float* s2 = smem + S2_OFF;
    float* s3 = smem;  // 2048 floats, aliases s0/s1 (dead by stage 3)

    const int b = blockIdx.x >> 3;
    const int q = blockIdx.x & 7;
    const int tid = threadIdx.x;
    const float bnscale = 0.99999500003749968f;

    // stage 0: points tile [3][263], zero-padded
    const int lo0 = 256 * q - 7;
    for (int t = tid; t < 3 * 263; t += 256) {
        int c = t / 263, j = t - c * 263;
        int p = lo0 + j;
        s0[c * S0_STR + j] = (p >= 0 && p < PP) ? pts[((size_t)b * 3 + c) * PP + p] : 0.f;
    }
    __syncthreads();

    // stage 1: conv1 + leaky + BN -> s1[32][131]
    const int lo1 = 128 * q - 3;
    for (int t = tid; t < 32 * 131; t += 256) {
        int ch = t / 131, j = t - ch * 131;
        int p1 = lo1 + j;
        float v = 0.f;
        if (p1 >= 0 && p1 < 1024) {
            float acc = c1b[ch];
            const float* w = c1W + ch * 9;
            const float* x0 = s0 + 2 * j;
#pragma unroll
            for (int ci = 0; ci < 3; ci++) {
                acc = fmaf(x0[ci * S0_STR + 0], w[ci * 3 + 0], acc);
                acc = fmaf(x0[ci * S0_STR + 1], w[ci * 3 + 1], acc);
                acc = fmaf(x0[ci * S0_STR + 2], w[ci * 3 + 2], acc);
            }
            acc = lrelu(acc, 0.01f);
            v = fmaf(acc, g1[ch] * bnscale, be1[ch]);
        }
        s1[ch * S1_STR + j] = v;
    }
    __syncthreads();

    // stage 2: conv2 + leaky + BN -> s2[64][65]
    const int lo2 = 64 * q - 1;
    for (int t = tid; t < 64 * 65; t += 256) {
        int ch = t / 65, j = t - ch * 65;
        int p2 = lo2 + j;
        float v = 0.f;
        if (p2 >= 0 && p2 < 512) {
            float acc = c2b[ch];
            const float* w = c2W + ch * 96;
            const float* x1 = s1 + 2 * j;
#pragma unroll
            for (int ci = 0; ci < 32; ci++) {
                acc = fmaf(x1[ci * S1_STR + 0], w[ci * 3 + 0], acc);
                acc = fmaf(x1[ci * S1_STR + 1], w[ci * 3 + 1], acc);
                acc = fmaf(x1[ci * S1_STR + 2], w[ci * 3 + 2], acc);
            }
            acc = lrelu(acc, 0.01f);
            v = fmaf(acc, g2[ch] * bnscale, be2[ch]);
        }
        s2[ch * S2_STR + j] = v;
    }
    __syncthreads();

    // stage 3: conv3 + leaky -> s3[64][32] (always-valid output positions)
    for (int t = tid; t < 64 * 32; t += 256) {
        int o = t >> 5, j = t & 31;
        float acc = c3b[o];
        const float* w = c3W + o * 192;
        const float* x2 = s2 + 2 * j;
#pragma unroll 16
        for (int ci = 0; ci < 64; ci++) {
            acc = fmaf(x2[ci * S2_STR + 0], w[ci * 3 + 0], acc);
            acc = fmaf(x2[ci * S2_STR + 1], w[ci * 3 + 1], acc);
            acc = fmaf(x2[ci * S2_STR + 2], w[ci * 3 + 2], acc);
        }
        s3[t] = lrelu(acc, 0.01f);
    }
    __syncthreads();

    // partial pool over this tile's 32 positions, per output channel
    if (tid < 64) {
        float s = 0.f;
#pragma unroll
        for (int j = 0; j < 32; j++) s += s3[tid * 32 + j];
        partials[((size_t)b * 8 + q) * 64 + tid] = s;
    }
}

// ---------------- head:  out = sigmoid(leaky(h@Wl2+bl2)@Wl3 + bl3) ----------------
__global__ void head_k(const float* __restrict__ hG, const float* __restrict__ partials,
                       const float* __restrict__ Wl2, const float* __restrict__ bl2,
                       const float* __restrict__ Wl3, const float* __restrict__ bl3,
                       float* __restrict__ out) {
    int b = blockIdx.x;
    int f = threadIdx.x;  // 64
    __shared__ float sh[64];
    float p = 0.f;
#pragma unroll
    for (int q = 0; q < 8; q++) p += partials[((size_t)b * 8 + q) * 64 + f];
    float h = hG[b * 64 + f] + p * (1.f / 256.f);
    sh[f] = h;
    __syncthreads();
    float acc = bl2[f];
#pragma unroll
    for (int k = 0; k < 64; k++) acc = fmaf(sh[k], Wl2[k * 64 + f], acc);
    acc = lrelu(acc, 0.01f);
    float pr = acc * Wl3[f];
#pragma unroll
    for (int off = 32; off > 0; off >>= 1) pr += __shfl_down(pr, off, 64);
    if (f == 0) out[b] = 1.f / (1.f + __expf(-(pr + bl3[0])));
}

extern "C" void kernel_launch(void* const* d_in, const int* in_sizes, int n_in,
                              void* d_out, int out_size, void* d_ws, size_t ws_size,
                              hipStream_t stream) {
    const float* x = (const float*)d_in[0];
    const int* ei = (const int*)d_in[1];
    const float* points = (const float*)d_in[2];
    const float* W1 = (const float*)d_in[3];
    const float* b1 = (const float*)d_in[4];
    const float* W2 = (const float*)d_in[5];
    const float* b2 = (const float*)d_in[6];
    const float* W3 = (const float*)d_in[7];
    const float* b3 = (const float*)d_in[8];
    const float* Wg1 = (const float*)d_in[9];
    const float* asrc1 = (const float*)d_in[10];
    const float* adst1 = (const float*)d_in[11];
    const float* bg1 = (const float*)d_in[12];
    const float* Wg2 = (const float*)d_in[13];
    const float* asrc2 = (const float*)d_in[14];
    const float* adst2 = (const float*)d_in[15];
    const float* bg2 = (const float*)d_in[16];
    const float* c1W = (const float*)d_in[17];
    const float* c1b = (const float*)d_in[18];
    const float* g1 = (const float*)d_in[19];
    const float* be1 = (const float*)d_in[20];
    const float* c2W = (const float*)d_in[21];
    const float* c2b = (const float*)d_in[22];
    const float* g2 = (const float*)d_in[23];
    const float* be2 = (const float*)d_in[24];
    const float* c3W = (const float*)d_in[25];
    const float* c3b = (const float*)d_in[26];
    const float* Wl2 = (const float*)d_in[27];
    const float* bl2 = (const float*)d_in[28];
    const float* Wl3 = (const float*)d_in[29];
    const float* bl3 = (const float*)d_in[30];

    const int* src = ei;
    const int* dst = ei + EE;

    // ---- workspace carve-up ----
    char* w = (char*)d_ws;
    size_t off = 0;
    auto A = [&](size_t bytes) -> void* {
        void* p = w + off;
        off = (off + bytes + 255) & ~(size_t)255;
        return p;
    };
    int* colb = (int*)A((size_t)EE * 4);
    int* rp = (int*)A((size_t)(NN + 1) * 4);
    int* cnt = (int*)A((size_t)NN * 4);
    int* bsum = (int*)A(256 * 4);
    int* boff = (int*)A(256 * 4);
    float* dinv = (float*)A((size_t)NN * 4);
    float* bufA = (float*)A((size_t)NN * 64 * 4);
    float* bufB = (float*)A((size_t)NN * 64 * 4);
    float* ew = (float*)A((size_t)EE * 4);
    float* wself = (float*)A((size_t)NN * 4);
    float* invden = (float*)A((size_t)NN * 4);
    float* es = (float*)A((size_t)NN * 4);
    float* edv = (float*)A((size_t)NN * 4);
    float* pooled = (float*)A((size_t)BB * CCROSS * 64 * 4);
    float* xw2 = (float*)A((size_t)BB * CCROSS * 64 * 4);
    float* es2 = (float*)A((size_t)BB * CCROSS * 4);
    float* ed2 = (float*)A((size_t)BB * CCROSS * 4);
    float* crosso = (float*)A((size_t)BB * CCROSS * 64 * 4);
    float* hG = (float*)A((size_t)BB * 64 * 4);
    float* partials = (float*)A((size_t)BB * 8 * 64 * 4);

    // ---- CSR build (dst-sorted) + dinv ----
    hipMemsetAsync(cnt, 0, (size_t)NN * 4, stream);
    hist_k<<<EE / 256, 256, 0, stream>>>(dst, cnt);
    dinv_k<<<NN / 256, 256, 0, stream>>>(cnt, dinv);
    scan_block_k<<<256, 1024, 0, stream>>>(cnt, rp, bsum);
    scan_top_k<<<1, 256, 0, stream>>>(bsum, boff);
    add_off_k<<<256, 1024, 0, stream>>>(rp, boff);
    hipMemsetAsync(cnt, 0, (size_t)NN * 4, stream);
    scatter_k<<<EE / 256, 256, 0, stream>>>(src, dst, rp, cnt, colb);

    // ---- points branch (independent; launch early so it can overlap in-graph) ----
    conv_fused_k<<<BB * 8, 256, 0, stream>>>(points, c1W, c1b, g1, be1, c2W, c2b, g2, be2, c3W, c3b, partials);

    // ---- GCN 1/2/3 ----
    gemm_k<19, 32, true, false><<<NN / 256, 256, 0, stream>>>(x, W1, dinv, bufA, nullptr, nullptr, nullptr, nullptr, NN);
    gcn_agg_k<32, 0><<<(NN * 32) / 256, 256, 0, stream>>>(bufA, rp, colb, dinv, b1, bufB);
    gemm_k<32, 64, true, false><<<NN / 256, 256, 0, stream>>>(bufB, W2, dinv, bufA, nullptr, nullptr, nullptr, nullptr, NN);
    gcn_agg_k<64, 1><<<(NN * 64) / 256, 256, 0, stream>>>(bufA, rp, colb, dinv, b2, bufB);
    gemm_k<64, 64, true, false><<<NN / 256, 256, 0, stream>>>(bufB, W3, dinv, bufA, nullptr, nullptr, nullptr, nullptr, NN);
    gcn_agg_k<64, 1><<<(NN * 64) / 256, 256, 0, stream>>>(bufA, rp, colb, dinv, b3, bufB);

    // ---- GAT 1 ----
    gemm_k<64, 64, false, true><<<NN / 256, 256, 0, stream>>>(bufB, Wg1, nullptr, bufA, asrc1, adst1, es, edv, NN);
    gat_w_k<<<NN / 256, 256, 0, stream>>>(es, edv, rp, colb, ew, wself, invden);
    gat_agg_k<<<(NN * 64) / 256, 256, 0, stream>>>(bufA, rp, colb, ew, wself, invden, bg1, bufB);

    // ---- pool pieces -> cross GAT -> pool cross ----
    pool_pieces_k<<<(BB * CCROSS * 64) / 256, 256, 0, stream>>>(bufB, pooled);
    gemm_k<64, 64, false, true><<<(BB * CCROSS) / 256, 256, 0, stream>>>(pooled, Wg2, nullptr, xw2, asrc2, adst2, es2, ed2, BB * CCROSS);
    cross_att_k<<<(BB * CCROSS * 64) / 256, 256, 0, stream>>>(xw2, es2, ed2, bg2, crosso);
    pool_cross_k<<<BB, 64, 0, stream>>>(crosso, hG);

    // ---- head ----
    head_k<<<BB, 64, 0, stream>>>(hG, partials, Wl2, bl2, Wl3, bl3, (float*)d_out);
}

// Round 3
// 986.673 us; speedup vs baseline: 2.2743x; 1.4501x over previous
//
#include <hip/hip_runtime.h>
#include <cstdint>
#include <cstddef>

#define NN 262144
#define EE 2097152
#define BB 64
#define CCROSS 32
#define PCC 128
#define PP 2048

static __device__ __forceinline__ float lrelu(float x, float s) { return x > 0.f ? x : s * x; }

// ---------------- CSR build ----------------
__global__ void hist_k(const int* __restrict__ dst, int* __restrict__ cnt) {
    int e = blockIdx.x * 256 + threadIdx.x;
    if (e >= EE) return;
    atomicAdd(&cnt[dst[e]], 1);
}

__global__ void dinv_k(const int* __restrict__ cnt, float* __restrict__ dinv) {
    int v = blockIdx.x * 256 + threadIdx.x;
    if (v >= NN) return;
    dinv[v] = rsqrtf((float)(cnt[v] + 1));
}

__global__ void scan_block_k(const int* __restrict__ in, int* __restrict__ out, int* __restrict__ bsum) {
    __shared__ int tmp[1024];
    int tid = threadIdx.x;
    int gid = blockIdx.x * 1024 + tid;
    int v = in[gid];
    tmp[tid] = v;
    __syncthreads();
    for (int off = 1; off < 1024; off <<= 1) {
        int t = (tid >= off) ? tmp[tid - off] : 0;
        __syncthreads();
        tmp[tid] += t;
        __syncthreads();
    }
    out[gid] = tmp[tid] - v;  // exclusive
    if (tid == 1023) bsum[blockIdx.x] = tmp[tid];
}

__global__ void scan_top_k(const int* __restrict__ bsum, int* __restrict__ boff) {
    __shared__ int tmp[256];
    int tid = threadIdx.x;
    int v = bsum[tid];
    tmp[tid] = v;
    __syncthreads();
    for (int off = 1; off < 256; off <<= 1) {
        int t = (tid >= off) ? tmp[tid - off] : 0;
        __syncthreads();
        tmp[tid] += t;
        __syncthreads();
    }
    boff[tid] = tmp[tid] - v;
}

__global__ void add_off_k(int* __restrict__ rp, const int* __restrict__ boff) {
    int gid = blockIdx.x * 1024 + threadIdx.x;
    rp[gid] += boff[blockIdx.x];
    if (gid == 0) rp[NN] = EE;
}

__global__ void scatter_k(const int* __restrict__ src, const int* __restrict__ dst,
                          const int* __restrict__ rp, int* __restrict__ fill, int* __restrict__ col) {
    int e = blockIdx.x * 256 + threadIdx.x;
    if (e >= EE) return;
    int d = dst[e];
    int pos = rp[d] + atomicAdd(&fill[d], 1);
    col[pos] = src[e];
}

// ---------------- skinny GEMM:  y[v] = (x[v] @ W) [* dinv[v]]  (+ es/ed dots) ----------------
template <int KIN, int KOUT, bool SCALE, bool ESED>
__global__ void gemm_k(const float* __restrict__ x, const float* __restrict__ W,
                       const float* __restrict__ dinv, float* __restrict__ y,
                       const float* __restrict__ av, const float* __restrict__ ad,
                       float* __restrict__ es, float* __restrict__ ed, int n) {
    int v = blockIdx.x * 256 + threadIdx.x;
    if (v >= n) return;
    const float* xr = x + (size_t)v * KIN;
    float acc[KOUT];
#pragma unroll
    for (int j = 0; j < KOUT; j++) acc[j] = 0.f;
#pragma unroll 2
    for (int k = 0; k < KIN; k++) {
        float xv = xr[k];
#pragma unroll
        for (int j = 0; j < KOUT; j++) acc[j] = fmaf(xv, W[k * KOUT + j], acc[j]);
    }
    float s = 1.f;
    if constexpr (SCALE) s = dinv[v];
    float e1 = 0.f, e2 = 0.f;
    float4* y4 = (float4*)(y + (size_t)v * KOUT);
#pragma unroll
    for (int j4 = 0; j4 < KOUT / 4; j4++) {
        float4 t;
        t.x = acc[4 * j4 + 0] * s;
        t.y = acc[4 * j4 + 1] * s;
        t.z = acc[4 * j4 + 2] * s;
        t.w = acc[4 * j4 + 3] * s;
        y4[j4] = t;
        if constexpr (ESED) {
            e1 = fmaf(t.x, av[4 * j4 + 0], e1); e1 = fmaf(t.y, av[4 * j4 + 1], e1);
            e1 = fmaf(t.z, av[4 * j4 + 2], e1); e1 = fmaf(t.w, av[4 * j4 + 3], e1);
            e2 = fmaf(t.x, ad[4 * j4 + 0], e2); e2 = fmaf(t.y, ad[4 * j4 + 1], e2);
            e2 = fmaf(t.z, ad[4 * j4 + 2], e2); e2 = fmaf(t.w, ad[4 * j4 + 3], e2);
        }
    }
    if constexpr (ESED) { es[v] = e1; ed[v] = e2; }
}

// ---------------- GCN aggregation (float4/lane, L float4s per node row, 4x edge unroll) ----------------
// L=8 for F=32 (8 nodes/wave), L=16 for F=64 (4 nodes/wave)
template <int L, int LOG2L, int ACT>  // ACT: 0 relu, 1 leaky 0.01
__global__ __launch_bounds__(256) void gcn_agg_k(const float* __restrict__ y, const int* __restrict__ rp,
                                                 const int* __restrict__ col, const float* __restrict__ dinv,
                                                 const float* __restrict__ bias, float* __restrict__ out) {
    int gid = blockIdx.x * 256 + threadIdx.x;
    int v = gid >> LOG2L;
    int idx = gid & (L - 1);
    const float4* y4 = (const float4*)y;
    float4 acc = y4[(size_t)v * L + idx];  // self loop (y pre-scaled by dinv)
    int s = rp[v], e = rp[v + 1];
    int i = s;
    for (; i + 4 <= e; i += 4) {
        int u0 = col[i], u1 = col[i + 1], u2 = col[i + 2], u3 = col[i + 3];
        float4 a0 = y4[(size_t)u0 * L + idx];
        float4 a1 = y4[(size_t)u1 * L + idx];
        float4 a2 = y4[(size_t)u2 * L + idx];
        float4 a3 = y4[(size_t)u3 * L + idx];
        acc.x += (a0.x + a1.x) + (a2.x + a3.x);
        acc.y += (a0.y + a1.y) + (a2.y + a3.y);
        acc.z += (a0.z + a1.z) + (a2.z + a3.z);
        acc.w += (a0.w + a1.w) + (a2.w + a3.w);
    }
    for (; i < e; i++) {
        float4 a = y4[(size_t)col[i] * L + idx];
        acc.x += a.x; acc.y += a.y; acc.z += a.z; acc.w += a.w;
    }
    float dv = dinv[v];
    const float4* b4 = (const float4*)bias;
    float4 bb = b4[idx];
    float4 r;
    r.x = acc.x * dv + bb.x; r.y = acc.y * dv + bb.y;
    r.z = acc.z * dv + bb.z; r.w = acc.w * dv + bb.w;
    if (ACT == 0) {
        r.x = fmaxf(r.x, 0.f); r.y = fmaxf(r.y, 0.f); r.z = fmaxf(r.z, 0.f); r.w = fmaxf(r.w, 0.f);
    } else {
        r.x = lrelu(r.x, 0.01f); r.y = lrelu(r.y, 0.01f); r.z = lrelu(r.z, 0.01f); r.w = lrelu(r.w, 0.01f);
    }
    ((float4*)out)[(size_t)v * L + idx] = r;
}

// ---------------- GAT edge softmax weights (per dst node; 2-pass, pass1 caches logits in ew) ----------------
__global__ void gat_w_k(const float* __restrict__ es, const float* __restrict__ ed,
                        const int* __restrict__ rp, const int* __restrict__ col,
                        float* __restrict__ ew, float* __restrict__ wself, float* __restrict__ invden) {
    int v = blockIdx.x * 256 + threadIdx.x;
    if (v >= NN) return;
    float edv = ed[v];
    float eself = lrelu(es[v] + edv, 0.2f);
    float m = eself;
    int s = rp[v], e = rp[v + 1];
    int i = s;
    for (; i + 4 <= e; i += 4) {
        int u0 = col[i], u1 = col[i + 1], u2 = col[i + 2], u3 = col[i + 3];
        float t0 = lrelu(es[u0] + edv, 0.2f);
        float t1 = lrelu(es[u1] + edv, 0.2f);
        float t2 = lrelu(es[u2] + edv, 0.2f);
        float t3 = lrelu(es[u3] + edv, 0.2f);
        ew[i] = t0; ew[i + 1] = t1; ew[i + 2] = t2; ew[i + 3] = t3;
        m = fmaxf(m, fmaxf(fmaxf(t0, t1), fmaxf(t2, t3)));
    }
    for (; i < e; i++) {
        float t = lrelu(es[col[i]] + edv, 0.2f);
        ew[i] = t;
        m = fmaxf(m, t);
    }
    float wsl = __expf(eself - m);
    float den = wsl;
    for (i = s; i < e; i++) {
        float w = __expf(ew[i] - m);
        ew[i] = w;
        den += w;
    }
    wself[v] = wsl;
    invden[v] = 1.f / den;
}

// ---------------- GAT aggregation (float4/lane, 16 float4s per row, 4x edge unroll) ----------------
__global__ __launch_bounds__(256) void gat_agg_k(const float* __restrict__ y, const int* __restrict__ rp,
                                                 const int* __restrict__ col, const float* __restrict__ ew,
                                                 const float* __restrict__ wself, const float* __restrict__ invden,
                                                 const float* __restrict__ bias, float* __restrict__ out) {
    int gid = blockIdx.x * 256 + threadIdx.x;
    int v = gid >> 4;
    int idx = gid & 15;
    const float4* y4 = (const float4*)y;
    float ws = wself[v];
    float4 self = y4[(size_t)v * 16 + idx];
    float4 acc;
    acc.x = ws * self.x; acc.y = ws * self.y; acc.z = ws * self.z; acc.w = ws * self.w;
    int s = rp[v], e = rp[v + 1];
    int i = s;
    for (; i + 4 <= e; i += 4) {
        int u0 = col[i], u1 = col[i + 1], u2 = col[i + 2], u3 = col[i + 3];
        float w0 = ew[i], w1 = ew[i + 1], w2 = ew[i + 2], w3 = ew[i + 3];
        float4 a0 = y4[(size_t)u0 * 16 + idx];
        float4 a1 = y4[(size_t)u1 * 16 + idx];
        float4 a2 = y4[(size_t)u2 * 16 + idx];
        float4 a3 = y4[(size_t)u3 * 16 + idx];
        acc.x = fmaf(w0, a0.x, fmaf(w1, a1.x, fmaf(w2, a2.x, fmaf(w3, a3.x, acc.x))));
        acc.y = fmaf(w0, a0.y, fmaf(w1, a1.y, fmaf(w2, a2.y, fmaf(w3, a3.y, acc.y))));
        acc.z = fmaf(w0, a0.z, fmaf(w1, a1.z, fmaf(w2, a2.z, fmaf(w3, a3.z, acc.z))));
        acc.w = fmaf(w0, a0.w, fmaf(w1, a1.w, fmaf(w2, a2.w, fmaf(w3, a3.w, acc.w))));
    }
    for (; i < e; i++) {
        float w = ew[i];
        float4 a = y4[(size_t)col[i] * 16 + idx];
        acc.x = fmaf(w, a.x, acc.x); acc.y = fmaf(w, a.y, acc.y);
        acc.z = fmaf(w, a.z, acc.z); acc.w = fmaf(w, a.w, acc.w);
    }
    float inv = invden[v];
    const float4* b4 = (const float4*)bias;
    float4 bb = b4[idx];
    float4 r;
    r.x = acc.x * inv + bb.x; r.y = acc.y * inv + bb.y;
    r.z = acc.z * inv + bb.z; r.w = acc.w * inv + bb.w;
    ((float4*)out)[(size_t)v * 16 + idx] = r;
}

// ---------------- pooling ----------------
__global__ void pool_pieces_k(const float* __restrict__ in, float* __restrict__ out) {
    int gid = blockIdx.x * 256 + threadIdx.x;  // 2048*64
    if (gid >= BB * CCROSS * 64) return;
    int f = gid & 63, g = gid >> 6;
    const float* p = in + (size_t)g * PCC * 64 + f;
    float s = 0.f;
#pragma unroll 8
    for (int i = 0; i < PCC; i++) s += p[(size_t)i * 64];
    out[gid] = s * (1.f / 128.f);
}

__global__ void pool_cross_k(const float* __restrict__ in, float* __restrict__ out) {
    int gid = blockIdx.x * 64 + threadIdx.x;  // 64*64
    if (gid >= BB * 64) return;
    int f = gid & 63, b = gid >> 6;
    const float* p = in + (size_t)b * CCROSS * 64 + f;
    float s = 0.f;
#pragma unroll
    for (int i = 0; i < CCROSS; i++) s += p[(size_t)i * 64];
    out[gid] = s * (1.f / 32.f);
}

// ---------------- dense cross-graph GAT (32 nodes/graph, multiplicity 2 off-diagonal) ----------------
__global__ void cross_att_k(const float* __restrict__ xw, const float* __restrict__ es,
                            const float* __restrict__ ed, const float* __restrict__ bg,
                            float* __restrict__ out) {
    int gid = blockIdx.x * 256 + threadIdx.x;  // 64*32*64
    if (gid >= BB * CCROSS * 64) return;
    int f = gid & 63;
    int d = (gid >> 6) & 31;
    int g = gid >> 11;
    int base = g * CCROSS;
    float edd = ed[base + d];
    float m = -1e30f;
#pragma unroll
    for (int s = 0; s < CCROSS; s++) {
        float e = lrelu(es[base + s] + edd, 0.2f);
        m = fmaxf(m, e);
    }
    float den = 0.f, acc = 0.f;
#pragma unroll
    for (int s = 0; s < CCROSS; s++) {
        float e = lrelu(es[base + s] + edd, 0.2f);
        float w = __expf(e - m) * ((s == d) ? 1.f : 2.f);
        den += w;
        acc = fmaf(w, xw[(size_t)(base + s) * 64 + f], acc);
    }
    out[gid] = acc / den + bg[f];
}

// ---------------- fused conv1->conv2->conv3->avgpool, per (batch, 32-wide conv3 tile) ----------------
#define S0_STR 264
#define S1_STR 132
#define S2_STR 66
#define S0_OFF 0
#define S1_OFF (3 * S0_STR)
#define S2_OFF (S1_OFF + 32 * S1_STR)
#define SMEM_FLOATS (S2_OFF + 64 * S2_STR)

__global__ __launch_bounds__(256) void conv_fused_k(
        const float* __restrict__ pts, const float* __restrict__ c1W, const float* __restrict__ c1b,
        const float* __restrict__ g1, const float* __restrict__ be1,
        const float* __restrict__ c2W, const float* __restrict__ c2b,
        const float* __restrict__ g2, const float* __restrict__ be2,
        const float* __restrict__ c3W, const float* __restrict__ c3b,
        float* __restrict__ partials /* [BB][8][64] */) {
    __shared__ float smem[SMEM_FLOATS];
    float* s0 = smem + S0_OFF;
    float* s1 = smem + S1_OFF;
    float* s2 = smem + S2_OFF;
    float* s3 = smem;  // 2048 floats, aliases s0/s1 (dead by stage 3)

    const int b = blockIdx.x >> 3;
    const int q = blockIdx.x & 7;
    const int tid = threadIdx.x;
    const float bnscale = 0.99999500003749968f;

    const int lo0 = 256 * q - 7;
    for (int t = tid; t < 3 * 263; t += 256) {
        int c = t / 263, j = t - c * 263;
        int p = lo0 + j;
        s0[c * S0_STR + j] = (p >= 0 && p < PP) ? pts[((size_t)b * 3 + c) * PP + p] : 0.f;
    }
    __syncthreads();

    const int lo1 = 128 * q - 3;
    for (int t = tid; t < 32 * 131; t += 256) {
        int ch = t / 131, j = t - ch * 131;
        int p1 = lo1 + j;
        float v = 0.f;
        if (p1 >= 0 && p1 < 1024) {
            float acc = c1b[ch];
            const float* w = c1W + ch * 9;
            const float* x0 = s0 + 2 * j;
#pragma unroll
            for (int ci = 0; ci < 3; ci++) {
                acc = fmaf(x0[ci * S0_STR + 0], w[ci * 3 + 0], acc);
                acc = fmaf(x0[ci * S0_STR + 1], w[ci * 3 + 1], acc);
                acc = fmaf(x0[ci * S0_STR + 2], w[ci * 3 + 2], acc);
            }
            acc = lrelu(acc, 0.01f);
            v = fmaf(acc, g1[ch] * bnscale, be1[ch]);
        }
        s1[ch * S1_STR + j] = v;
    }
    __syncthreads();

    const int lo2 = 64 * q - 1;
    for (int t = tid; t < 64 * 65; t += 256) {
        int ch = t / 65, j = t - ch * 65;
        int p2 = lo2 + j;
        float v = 0.f;
        if (p2 >= 0 && p2 < 512) {
            float acc = c2b[ch];
            const float* w = c2W + ch * 96;
            const float* x1 = s1 + 2 * j;
#pragma unroll
            for (int ci = 0; ci < 32; ci++) {
                acc = fmaf(x1[ci * S1_STR + 0], w[ci * 3 + 0], acc);
                acc = fmaf(x1[ci * S1_STR + 1], w[ci * 3 + 1], acc);
                acc = fmaf(x1[ci * S1_STR + 2], w[ci * 3 + 2], acc);
            }
            acc = lrelu(acc, 0.01f);
            v = fmaf(acc, g2[ch] * bnscale, be2[ch]);
        }
        s2[ch * S2_STR + j] = v;
    }
    __syncthreads();

    for (int t = tid; t < 64 * 32; t += 256) {
        int o = t >> 5, j = t & 31;
        float acc = c3b[o];
        const float* w = c3W + o * 192;
        const float* x2 = s2 + 2 * j;
#pragma unroll 16
        for (int ci = 0; ci < 64; ci++) {
            acc = fmaf(x2[ci * S2_STR + 0], w[ci * 3 + 0], acc);
            acc = fmaf(x2[ci * S2_STR + 1], w[ci * 3 + 1], acc);
            acc = fmaf(x2[ci * S2_STR + 2], w[ci * 3 + 2], acc);
        }
        s3[t] = lrelu(acc, 0.01f);
    }
    __syncthreads();

    if (tid < 64) {
        float s = 0.f;
#pragma unroll
        for (int j = 0; j < 32; j++) s += s3[tid * 32 + j];
        partials[((size_t)b * 8 + q) * 64 + tid] = s;
    }
}

// ---------------- head:  out = sigmoid(leaky(h@Wl2+bl2)@Wl3 + bl3) ----------------
__global__ void head_k(const float* __restrict__ hG, const float* __restrict__ partials,
                       const float* __restrict__ Wl2, const float* __restrict__ bl2,
                       const float* __restrict__ Wl3, const float* __restrict__ bl3,
                       float* __restrict__ out) {
    int b = blockIdx.x;
    int f = threadIdx.x;  // 64
    __shared__ float sh[64];
    float p = 0.f;
#pragma unroll
    for (int q = 0; q < 8; q++) p += partials[((size_t)b * 8 + q) * 64 + f];
    float h = hG[b * 64 + f] + p * (1.f / 256.f);
    sh[f] = h;
    __syncthreads();
    float acc = bl2[f];
#pragma unroll
    for (int k = 0; k < 64; k++) acc = fmaf(sh[k], Wl2[k * 64 + f], acc);
    acc = lrelu(acc, 0.01f);
    float pr = acc * Wl3[f];
#pragma unroll
    for (int off = 32; off > 0; off >>= 1) pr += __shfl_down(pr, off, 64);
    if (f == 0) out[b] = 1.f / (1.f + __expf(-(pr + bl3[0])));
}

extern "C" void kernel_launch(void* const* d_in, const int* in_sizes, int n_in,
                              void* d_out, int out_size, void* d_ws, size_t ws_size,
                              hipStream_t stream) {
    const float* x = (const float*)d_in[0];
    const int* ei = (const int*)d_in[1];
    const float* points = (const float*)d_in[2];
    const float* W1 = (const float*)d_in[3];
    const float* b1 = (const float*)d_in[4];
    const float* W2 = (const float*)d_in[5];
    const float* b2 = (const float*)d_in[6];
    const float* W3 = (const float*)d_in[7];
    const float* b3 = (const float*)d_in[8];
    const float* Wg1 = (const float*)d_in[9];
    const float* asrc1 = (const float*)d_in[10];
    const float* adst1 = (const float*)d_in[11];
    const float* bg1 = (const float*)d_in[12];
    const float* Wg2 = (const float*)d_in[13];
    const float* asrc2 = (const float*)d_in[14];
    const float* adst2 = (const float*)d_in[15];
    const float* bg2 = (const float*)d_in[16];
    const float* c1W = (const float*)d_in[17];
    const float* c1b = (const float*)d_in[18];
    const float* g1 = (const float*)d_in[19];
    const float* be1 = (const float*)d_in[20];
    const float* c2W = (const float*)d_in[21];
    const float* c2b = (const float*)d_in[22];
    const float* g2 = (const float*)d_in[23];
    const float* be2 = (const float*)d_in[24];
    const float* c3W = (const float*)d_in[25];
    const float* c3b = (const float*)d_in[26];
    const float* Wl2 = (const float*)d_in[27];
    const float* bl2 = (const float*)d_in[28];
    const float* Wl3 = (const float*)d_in[29];
    const float* bl3 = (const float*)d_in[30];

    const int* src = ei;
    const int* dst = ei + EE;

    // ---- workspace carve-up ----
    char* w = (char*)d_ws;
    size_t off = 0;
    auto A = [&](size_t bytes) -> void* {
        void* p = w + off;
        off = (off + bytes + 255) & ~(size_t)255;
        return p;
    };
    int* colb = (int*)A((size_t)EE * 4);
    int* rp = (int*)A((size_t)(NN + 1) * 4);
    int* cnt = (int*)A((size_t)NN * 4);
    int* bsum = (int*)A(256 * 4);
    int* boff = (int*)A(256 * 4);
    float* dinv = (float*)A((size_t)NN * 4);
    float* bufA = (float*)A((size_t)NN * 64 * 4);
    float* bufB = (float*)A((size_t)NN * 64 * 4);
    float* ew = (float*)A((size_t)EE * 4);
    float* wself = (float*)A((size_t)NN * 4);
    float* invden = (float*)A((size_t)NN * 4);
    float* es = (float*)A((size_t)NN * 4);
    float* edv = (float*)A((size_t)NN * 4);
    float* pooled = (float*)A((size_t)BB * CCROSS * 64 * 4);
    float* xw2 = (float*)A((size_t)BB * CCROSS * 64 * 4);
    float* es2 = (float*)A((size_t)BB * CCROSS * 4);
    float* ed2 = (float*)A((size_t)BB * CCROSS * 4);
    float* crosso = (float*)A((size_t)BB * CCROSS * 64 * 4);
    float* hG = (float*)A((size_t)BB * 64 * 4);
    float* partials = (float*)A((size_t)BB * 8 * 64 * 4);

    // ---- CSR build (dst-sorted) + dinv ----
    hipMemsetAsync(cnt, 0, (size_t)NN * 4, stream);
    hist_k<<<EE / 256, 256, 0, stream>>>(dst, cnt);
    dinv_k<<<NN / 256, 256, 0, stream>>>(cnt, dinv);
    scan_block_k<<<256, 1024, 0, stream>>>(cnt, rp, bsum);
    scan_top_k<<<1, 256, 0, stream>>>(bsum, boff);
    add_off_k<<<256, 1024, 0, stream>>>(rp, boff);
    hipMemsetAsync(cnt, 0, (size_t)NN * 4, stream);
    scatter_k<<<EE / 256, 256, 0, stream>>>(src, dst, rp, cnt, colb);

    // ---- points branch (independent) ----
    conv_fused_k<<<BB * 8, 256, 0, stream>>>(points, c1W, c1b, g1, be1, c2W, c2b, g2, be2, c3W, c3b, partials);

    // ---- GCN 1/2/3 ----
    gemm_k<19, 32, true, false><<<NN / 256, 256, 0, stream>>>(x, W1, dinv, bufA, nullptr, nullptr, nullptr, nullptr, NN);
    gcn_agg_k<8, 3, 0><<<(NN * 8) / 256, 256, 0, stream>>>(bufA, rp, colb, dinv, b1, bufB);
    gemm_k<32, 64, true, false><<<NN / 256, 256, 0, stream>>>(bufB, W2, dinv, bufA, nullptr, nullptr, nullptr, nullptr, NN);
    gcn_agg_k<16, 4, 1><<<(NN * 16) / 256, 256, 0, stream>>>(bufA, rp, colb, dinv, b2, bufB);
    gemm_k<64, 64, true, false><<<NN / 256, 256, 0, stream>>>(bufB, W3, dinv, bufA, nullptr, nullptr, nullptr, nullptr, NN);
    gcn_agg_k<16, 4, 1><<<(NN * 16) / 256, 256, 0, stream>>>(bufA, rp, colb, dinv, b3, bufB);

    // ---- GAT 1 ----
    gemm_k<64, 64, false, true><<<NN / 256, 256, 0, stream>>>(bufB, Wg1, nullptr, bufA, asrc1, adst1, es, edv, NN);
    gat_w_k<<<NN / 256, 256, 0, stream>>>(es, edv, rp, colb, ew, wself, invden);
    gat_agg_k<<<(NN * 16) / 256, 256, 0, stream>>>(bufA, rp, colb, ew, wself, invden, bg1, bufB);

    // ---- pool pieces -> cross GAT -> pool cross ----
    pool_pieces_k<<<(BB * CCROSS * 64) / 256, 256, 0, stream>>>(bufB, pooled);
    gemm_k<64, 64, false, true><<<(BB * CCROSS) / 256, 256, 0, stream>>>(pooled, Wg2, nullptr, xw2, asrc2, adst2, es2, ed2, BB * CCROSS);
    cross_att_k<<<(BB * CCROSS * 64) / 256, 256, 0, stream>>>(xw2, es2, ed2, bg2, crosso);
    pool_cross_k<<<BB, 64, 0, stream>>>(crosso, hG);

    // ---- head ----
    head_k<<<BB, 64, 0, stream>>>(hG, partials, Wl2, bl2, Wl3, bl3, (float*)d_out);
}

// Round 4
// 797.874 us; speedup vs baseline: 2.8124x; 1.2366x over previous
//
#include <hip/hip_runtime.h>
#include <cstdint>
#include <cstddef>

#define NN 262144
#define EE 2097152
#define BB 64
#define CCROSS 32
#define PCC 128
#define PP 2048
#define NBUCK 256
#define BCAP 12288  // expected 8192 +- ~90 sigma; huge margin

static __device__ __forceinline__ float lrelu(float x, float s) { return x > 0.f ? x : s * x; }

// ---------------- bucketed CSR build ----------------
// Pass A: scatter edges into 256 dst-range buckets, packed (src<<10)|dst_local.
__global__ __launch_bounds__(256) void bucket_a_k(const int* __restrict__ src, const int* __restrict__ dst,
                                                  unsigned* __restrict__ buckets, int* __restrict__ gcnt) {
    __shared__ int hist[NBUCK];
    __shared__ int base[NBUCK];
    __shared__ unsigned short rankbuf[8192];
    const int tid = threadIdx.x;
    const int e0 = blockIdx.x * 8192;
    hist[tid] = 0;
    __syncthreads();
    for (int i = tid; i < 8192; i += 256) {
        int d = dst[e0 + i];
        rankbuf[i] = (unsigned short)atomicAdd(&hist[d >> 10], 1);
    }
    __syncthreads();
    base[tid] = tid * BCAP + atomicAdd(&gcnt[tid], hist[tid]);
    __syncthreads();
    for (int i = tid; i < 8192; i += 256) {
        int s = src[e0 + i];
        int d = dst[e0 + i];
        int b = d >> 10;
        buckets[base[b] + rankbuf[i]] = ((unsigned)s << 10) | (unsigned)(d & 1023);
    }
}

__global__ void bucket_scan_k(const int* __restrict__ gcnt, int* __restrict__ bbase, int* __restrict__ rp) {
    __shared__ int tmp[256];
    int tid = threadIdx.x;
    int v = gcnt[tid];
    tmp[tid] = v;
    __syncthreads();
    for (int off = 1; off < 256; off <<= 1) {
        int t = (tid >= off) ? tmp[tid - off] : 0;
        __syncthreads();
        tmp[tid] += t;
        __syncthreads();
    }
    bbase[tid] = tmp[tid] - v;
    if (tid == 0) rp[NN] = EE;
}

// Pass B: per-bucket histogram over 1024 nodes, LDS scan, write rp/dinv, scatter col.
__global__ __launch_bounds__(256) void bucket_b_k(const unsigned* __restrict__ buckets, const int* __restrict__ gcnt,
                                                  const int* __restrict__ bbase, int* __restrict__ rp,
                                                  float* __restrict__ dinv, int* __restrict__ col) {
    __shared__ int cnt[1024];
    __shared__ int scan[1024];
    __shared__ int wsum[256];
    const int b = blockIdx.x;
    const int tid = threadIdx.x;
    int n = gcnt[b];
    if (n > BCAP) n = BCAP;
    const unsigned* eb = buckets + (size_t)b * BCAP;
    const int gb = bbase[b];
    for (int i = tid; i < 1024; i += 256) cnt[i] = 0;
    __syncthreads();
    for (int i = tid; i < n; i += 256) atomicAdd(&cnt[eb[i] & 1023], 1);
    __syncthreads();
    int b4 = tid * 4;
    int c0 = cnt[b4], c1 = cnt[b4 + 1], c2 = cnt[b4 + 2], c3 = cnt[b4 + 3];
    int tsum = c0 + c1 + c2 + c3;
    wsum[tid] = tsum;
    __syncthreads();
    for (int off = 1; off < 256; off <<= 1) {
        int t = (tid >= off) ? wsum[tid - off] : 0;
        __syncthreads();
        wsum[tid] += t;
        __syncthreads();
    }
    int excl = wsum[tid] - tsum;
    scan[b4] = excl;
    scan[b4 + 1] = excl + c0;
    scan[b4 + 2] = excl + c0 + c1;
    scan[b4 + 3] = excl + c0 + c1 + c2;
    int vbase = b * 1024 + b4;
    rp[vbase + 0] = gb + scan[b4 + 0];
    rp[vbase + 1] = gb + scan[b4 + 1];
    rp[vbase + 2] = gb + scan[b4 + 2];
    rp[vbase + 3] = gb + scan[b4 + 3];
    dinv[vbase + 0] = rsqrtf((float)(c0 + 1));
    dinv[vbase + 1] = rsqrtf((float)(c1 + 1));
    dinv[vbase + 2] = rsqrtf((float)(c2 + 1));
    dinv[vbase + 3] = rsqrtf((float)(c3 + 1));
    __syncthreads();
    for (int i = tid; i < 1024; i += 256) cnt[i] = 0;
    __syncthreads();
    for (int i = tid; i < n; i += 256) {
        unsigned p = eb[i];
        int dl = p & 1023;
        int r = atomicAdd(&cnt[dl], 1);
        col[gb + scan[dl] + r] = (int)(p >> 10);
    }
}

// ---------------- z-prep: z[v] = dinv[v]*x[v], padded 19 -> 20 ----------------
__global__ void zprep_k(const float* __restrict__ x, const float* __restrict__ dinv, float* __restrict__ z) {
    int v = blockIdx.x * 256 + threadIdx.x;
    if (v >= NN) return;
    float dv = dinv[v];
    const float* xr = x + (size_t)v * 19;
    float* zr = z + (size_t)v * 20;
#pragma unroll
    for (int k = 0; k < 19; k++) zr[k] = dv * xr[k];
    zr[19] = 0.f;
}

// ---------------- plain sum aggregation (self + neighbors), float4/lane, L float4 per row ----------------
template <int L>
__global__ __launch_bounds__(256) void agg_sum_k(const float* __restrict__ y, const int* __restrict__ rp,
                                                 const int* __restrict__ col, float* __restrict__ out) {
    int gid = blockIdx.x * 256 + threadIdx.x;
    int v = gid / L;
    int idx = gid - v * L;
    if (v >= NN) return;
    const float4* y4 = (const float4*)y;
    float4 acc = y4[(size_t)v * L + idx];  // self loop
    int s = rp[v], e = rp[v + 1];
    int i = s;
    for (; i + 4 <= e; i += 4) {
        int u0 = col[i], u1 = col[i + 1], u2 = col[i + 2], u3 = col[i + 3];
        float4 a0 = y4[(size_t)u0 * L + idx];
        float4 a1 = y4[(size_t)u1 * L + idx];
        float4 a2 = y4[(size_t)u2 * L + idx];
        float4 a3 = y4[(size_t)u3 * L + idx];
        acc.x += (a0.x + a1.x) + (a2.x + a3.x);
        acc.y += (a0.y + a1.y) + (a2.y + a3.y);
        acc.z += (a0.z + a1.z) + (a2.z + a3.z);
        acc.w += (a0.w + a1.w) + (a2.w + a3.w);
    }
    for (; i < e; i++) {
        float4 a = y4[(size_t)col[i] * L + idx];
        acc.x += a.x; acc.y += a.y; acc.z += a.z; acc.w += a.w;
    }
    ((float4*)out)[(size_t)v * L + idx] = acc;
}

// ---------------- GCN gemm: out = act(dinv*(in@W) + b), optionally pre-scaled by dinv for next layer ----------------
template <int KIN, int STRIDE, int KOUT, int ACT, bool WRITEZ>  // ACT: 0 relu, 1 leaky 0.01
__global__ __launch_bounds__(256) void gcn_gemm_k(const float* __restrict__ x, const float* __restrict__ W,
                                                  const float* __restrict__ dinv, const float* __restrict__ bias,
                                                  float* __restrict__ y) {
    int v = blockIdx.x * 256 + threadIdx.x;
    if (v >= NN) return;
    const float* xr = x + (size_t)v * STRIDE;
    float acc[KOUT];
#pragma unroll
    for (int j = 0; j < KOUT; j++) acc[j] = 0.f;
#pragma unroll 2
    for (int k = 0; k < KIN; k++) {
        float xv = xr[k];
#pragma unroll
        for (int j = 0; j < KOUT; j++) acc[j] = fmaf(xv, W[k * KOUT + j], acc[j]);
    }
    float dv = dinv[v];
    float4* y4 = (float4*)(y + (size_t)v * KOUT);
#pragma unroll
    for (int j4 = 0; j4 < KOUT / 4; j4++) {
        float4 t;
        t.x = dv * acc[4 * j4 + 0] + bias[4 * j4 + 0];
        t.y = dv * acc[4 * j4 + 1] + bias[4 * j4 + 1];
        t.z = dv * acc[4 * j4 + 2] + bias[4 * j4 + 2];
        t.w = dv * acc[4 * j4 + 3] + bias[4 * j4 + 3];
        if (ACT == 0) {
            t.x = fmaxf(t.x, 0.f); t.y = fmaxf(t.y, 0.f); t.z = fmaxf(t.z, 0.f); t.w = fmaxf(t.w, 0.f);
        } else {
            t.x = lrelu(t.x, 0.01f); t.y = lrelu(t.y, 0.01f); t.z = lrelu(t.z, 0.01f); t.w = lrelu(t.w, 0.01f);
        }
        if (WRITEZ) { t.x *= dv; t.y *= dv; t.z *= dv; t.w *= dv; }
        y4[j4] = t;
    }
}

// ---------------- GAT input gemm:  y[v] = x[v] @ W  (+ es/ed dots) ----------------
template <int KIN, int KOUT>
__global__ void gat_gemm_k(const float* __restrict__ x, const float* __restrict__ W,
                           float* __restrict__ y, const float* __restrict__ av, const float* __restrict__ ad,
                           float* __restrict__ es, float* __restrict__ ed, int n) {
    int v = blockIdx.x * 256 + threadIdx.x;
    if (v >= n) return;
    const float* xr = x + (size_t)v * KIN;
    float acc[KOUT];
#pragma unroll
    for (int j = 0; j < KOUT; j++) acc[j] = 0.f;
#pragma unroll 2
    for (int k = 0; k < KIN; k++) {
        float xv = xr[k];
#pragma unroll
        for (int j = 0; j < KOUT; j++) acc[j] = fmaf(xv, W[k * KOUT + j], acc[j]);
    }
    float e1 = 0.f, e2 = 0.f;
    float4* y4 = (float4*)(y + (size_t)v * KOUT);
#pragma unroll
    for (int j4 = 0; j4 < KOUT / 4; j4++) {
        float4 t;
        t.x = acc[4 * j4 + 0]; t.y = acc[4 * j4 + 1]; t.z = acc[4 * j4 + 2]; t.w = acc[4 * j4 + 3];
        y4[j4] = t;
        e1 = fmaf(t.x, av[4 * j4 + 0], e1); e1 = fmaf(t.y, av[4 * j4 + 1], e1);
        e1 = fmaf(t.z, av[4 * j4 + 2], e1); e1 = fmaf(t.w, av[4 * j4 + 3], e1);
        e2 = fmaf(t.x, ad[4 * j4 + 0], e2); e2 = fmaf(t.y, ad[4 * j4 + 1], e2);
        e2 = fmaf(t.z, ad[4 * j4 + 2], e2); e2 = fmaf(t.w, ad[4 * j4 + 3], e2);
    }
    es[v] = e1; ed[v] = e2;
}

// ---------------- GAT edge softmax weights ----------------
__global__ void gat_w_k(const float* __restrict__ es, const float* __restrict__ ed,
                        const int* __restrict__ rp, const int* __restrict__ col,
                        float* __restrict__ ew, float* __restrict__ wself, float* __restrict__ invden) {
    int v = blockIdx.x * 256 + threadIdx.x;
    if (v >= NN) return;
    float edv = ed[v];
    float eself = lrelu(es[v] + edv, 0.2f);
    float m = eself;
    int s = rp[v], e = rp[v + 1];
    int i = s;
    for (; i + 4 <= e; i += 4) {
        int u0 = col[i], u1 = col[i + 1], u2 = col[i + 2], u3 = col[i + 3];
        float t0 = lrelu(es[u0] + edv, 0.2f);
        float t1 = lrelu(es[u1] + edv, 0.2f);
        float t2 = lrelu(es[u2] + edv, 0.2f);
        float t3 = lrelu(es[u3] + edv, 0.2f);
        ew[i] = t0; ew[i + 1] = t1; ew[i + 2] = t2; ew[i + 3] = t3;
        m = fmaxf(m, fmaxf(fmaxf(t0, t1), fmaxf(t2, t3)));
    }
    for (; i < e; i++) {
        float t = lrelu(es[col[i]] + edv, 0.2f);
        ew[i] = t;
        m = fmaxf(m, t);
    }
    float wsl = __expf(eself - m);
    float den = wsl;
    for (i = s; i < e; i++) {
        float w = __expf(ew[i] - m);
        ew[i] = w;
        den += w;
    }
    wself[v] = wsl;
    invden[v] = 1.f / den;
}

// ---------------- GAT aggregation ----------------
__global__ __launch_bounds__(256) void gat_agg_k(const float* __restrict__ y, const int* __restrict__ rp,
                                                 const int* __restrict__ col, const float* __restrict__ ew,
                                                 const float* __restrict__ wself, const float* __restrict__ invden,
                                                 const float* __restrict__ bias, float* __restrict__ out) {
    int gid = blockIdx.x * 256 + threadIdx.x;
    int v = gid >> 4;
    int idx = gid & 15;
    const float4* y4 = (const float4*)y;
    float ws = wself[v];
    float4 self = y4[(size_t)v * 16 + idx];
    float4 acc;
    acc.x = ws * self.x; acc.y = ws * self.y; acc.z = ws * self.z; acc.w = ws * self.w;
    int s = rp[v], e = rp[v + 1];
    int i = s;
    for (; i + 4 <= e; i += 4) {
        int u0 = col[i], u1 = col[i + 1], u2 = col[i + 2], u3 = col[i + 3];
        float w0 = ew[i], w1 = ew[i + 1], w2 = ew[i + 2], w3 = ew[i + 3];
        float4 a0 = y4[(size_t)u0 * 16 + idx];
        float4 a1 = y4[(size_t)u1 * 16 + idx];
        float4 a2 = y4[(size_t)u2 * 16 + idx];
        float4 a3 = y4[(size_t)u3 * 16 + idx];
        acc.x = fmaf(w0, a0.x, fmaf(w1, a1.x, fmaf(w2, a2.x, fmaf(w3, a3.x, acc.x))));
        acc.y = fmaf(w0, a0.y, fmaf(w1, a1.y, fmaf(w2, a2.y, fmaf(w3, a3.y, acc.y))));
        acc.z = fmaf(w0, a0.z, fmaf(w1, a1.z, fmaf(w2, a2.z, fmaf(w3, a3.z, acc.z))));
        acc.w = fmaf(w0, a0.w, fmaf(w1, a1.w, fmaf(w2, a2.w, fmaf(w3, a3.w, acc.w))));
    }
    for (; i < e; i++) {
        float w = ew[i];
        float4 a = y4[(size_t)col[i] * 16 + idx];
        acc.x = fmaf(w, a.x, acc.x); acc.y = fmaf(w, a.y, acc.y);
        acc.z = fmaf(w, a.z, acc.z); acc.w = fmaf(w, a.w, acc.w);
    }
    float inv = invden[v];
    const float4* b4 = (const float4*)bias;
    float4 bb = b4[idx];
    float4 r;
    r.x = acc.x * inv + bb.x; r.y = acc.y * inv + bb.y;
    r.z = acc.z * inv + bb.z; r.w = acc.w * inv + bb.w;
    ((float4*)out)[(size_t)v * 16 + idx] = r;
}

// ---------------- pooling ----------------
__global__ void pool_pieces_k(const float* __restrict__ in, float* __restrict__ out) {
    int gid = blockIdx.x * 256 + threadIdx.x;
    if (gid >= BB * CCROSS * 64) return;
    int f = gid & 63, g = gid >> 6;
    const float* p = in + (size_t)g * PCC * 64 + f;
    float s = 0.f;
#pragma unroll 8
    for (int i = 0; i < PCC; i++) s += p[(size_t)i * 64];
    out[gid] = s * (1.f / 128.f);
}

__global__ void pool_cross_k(const float* __restrict__ in, float* __restrict__ out) {
    int gid = blockIdx.x * 64 + threadIdx.x;
    if (gid >= BB * 64) return;
    int f = gid & 63, b = gid >> 6;
    const float* p = in + (size_t)b * CCROSS * 64 + f;
    float s = 0.f;
#pragma unroll
    for (int i = 0; i < CCROSS; i++) s += p[(size_t)i * 64];
    out[gid] = s * (1.f / 32.f);
}

// ---------------- dense cross-graph GAT ----------------
__global__ void cross_att_k(const float* __restrict__ xw, const float* __restrict__ es,
                            const float* __restrict__ ed, const float* __restrict__ bg,
                            float* __restrict__ out) {
    int gid = blockIdx.x * 256 + threadIdx.x;
    if (gid >= BB * CCROSS * 64) return;
    int f = gid & 63;
    int d = (gid >> 6) & 31;
    int g = gid >> 11;
    int base = g * CCROSS;
    float edd = ed[base + d];
    float m = -1e30f;
#pragma unroll
    for (int s = 0; s < CCROSS; s++) {
        float e = lrelu(es[base + s] + edd, 0.2f);
        m = fmaxf(m, e);
    }
    float den = 0.f, acc = 0.f;
#pragma unroll
    for (int s = 0; s < CCROSS; s++) {
        float e = lrelu(es[base + s] + edd, 0.2f);
        float w = __expf(e - m) * ((s == d) ? 1.f : 2.f);
        den += w;
        acc = fmaf(w, xw[(size_t)(base + s) * 64 + f], acc);
    }
    out[gid] = acc / den + bg[f];
}

// ---------------- fused conv branch ----------------
#define S0_STR 264
#define S1_STR 132
#define S2_STR 66
#define S0_OFF 0
#define S1_OFF (3 * S0_STR)
#define S2_OFF (S1_OFF + 32 * S1_STR)
#define SMEM_FLOATS (S2_OFF + 64 * S2_STR)

__global__ __launch_bounds__(256) void conv_fused_k(
        const float* __restrict__ pts, const float* __restrict__ c1W, const float* __restrict__ c1b,
        const float* __restrict__ g1, const float* __restrict__ be1,
        const float* __restrict__ c2W, const float* __restrict__ c2b,
        const float* __restrict__ g2, const float* __restrict__ be2,
        const float* __restrict__ c3W, const float* __restrict__ c3b,
        float* __restrict__ partials) {
    __shared__ float smem[SMEM_FLOATS];
    float* s0 = smem + S0_OFF;
    float* s1 = smem + S1_OFF;
    float* s2 = smem + S2_OFF;
    float* s3 = smem;

    const int b = blockIdx.x >> 3;
    const int q = blockIdx.x & 7;
    const int tid = threadIdx.x;
    const float bnscale = 0.99999500003749968f;

    const int lo0 = 256 * q - 7;
    for (int t = tid; t < 3 * 263; t += 256) {
        int c = t / 263, j = t - c * 263;
        int p = lo0 + j;
        s0[c * S0_STR + j] = (p >= 0 && p < PP) ? pts[((size_t)b * 3 + c) * PP + p] : 0.f;
    }
    __syncthreads();

    const int lo1 = 128 * q - 3;
    for (int t = tid; t < 32 * 131; t += 256) {
        int ch = t / 131, j = t - ch * 131;
        int p1 = lo1 + j;
        float v = 0.f;
        if (p1 >= 0 && p1 < 1024) {
            float acc = c1b[ch];
            const float* w = c1W + ch * 9;
            const float* x0 = s0 + 2 * j;
#pragma unroll
            for (int ci = 0; ci < 3; ci++) {
                acc = fmaf(x0[ci * S0_STR + 0], w[ci * 3 + 0], acc);
                acc = fmaf(x0[ci * S0_STR + 1], w[ci * 3 + 1], acc);
                acc = fmaf(x0[ci * S0_STR + 2], w[ci * 3 + 2], acc);
            }
            acc = lrelu(acc, 0.01f);
            v = fmaf(acc, g1[ch] * bnscale, be1[ch]);
        }
        s1[ch * S1_STR + j] = v;
    }
    __syncthreads();

    const int lo2 = 64 * q - 1;
    for (int t = tid; t < 64 * 65; t += 256) {
        int ch = t / 65, j = t - ch * 65;
        int p2 = lo2 + j;
        float v = 0.f;
        if (p2 >= 0 && p2 < 512) {
            float acc = c2b[ch];
            const float* w = c2W + ch * 96;
            const float* x1 = s1 + 2 * j;
#pragma unroll
            for (int ci = 0; ci < 32; ci++) {
                acc = fmaf(x1[ci * S1_STR + 0], w[ci * 3 + 0], acc);
                acc = fmaf(x1[ci * S1_STR + 1], w[ci * 3 + 1], acc);
                acc = fmaf(x1[ci * S1_STR + 2], w[ci * 3 + 2], acc);
            }
            acc = lrelu(acc, 0.01f);
            v = fmaf(acc, g2[ch] * bnscale, be2[ch]);
        }
        s2[ch * S2_STR + j] = v;
    }
    __syncthreads();

    for (int t = tid; t < 64 * 32; t += 256) {
        int o = t >> 5, j = t & 31;
        float acc = c3b[o];
        const float* w = c3W + o * 192;
        const float* x2 = s2 + 2 * j;
#pragma unroll 16
        for (int ci = 0; ci < 64; ci++) {
            acc = fmaf(x2[ci * S2_STR + 0], w[ci * 3 + 0], acc);
            acc = fmaf(x2[ci * S2_STR + 1], w[ci * 3 + 1], acc);
            acc = fmaf(x2[ci * S2_STR + 2], w[ci * 3 + 2], acc);
        }
        s3[t] = lrelu(acc, 0.01f);
    }
    __syncthreads();

    if (tid < 64) {
        float s = 0.f;
#pragma unroll
        for (int j = 0; j < 32; j++) s += s3[tid * 32 + j];
        partials[((size_t)b * 8 + q) * 64 + tid] = s;
    }
}

// ---------------- head ----------------
__global__ void head_k(const float* __restrict__ hG, const float* __restrict__ partials,
                       const float* __restrict__ Wl2, const float* __restrict__ bl2,
                       const float* __restrict__ Wl3, const float* __restrict__ bl3,
                       float* __restrict__ out) {
    int b = blockIdx.x;
    int f = threadIdx.x;  // 64
    __shared__ float sh[64];
    float p = 0.f;
#pragma unroll
    for (int q = 0; q < 8; q++) p += partials[((size_t)b * 8 + q) * 64 + f];
    float h = hG[b * 64 + f] + p * (1.f / 256.f);
    sh[f] = h;
    __syncthreads();
    float acc = bl2[f];
#pragma unroll
    for (int k = 0; k < 64; k++) acc = fmaf(sh[k], Wl2[k * 64 + f], acc);
    acc = lrelu(acc, 0.01f);
    float pr = acc * Wl3[f];
#pragma unroll
    for (int off = 32; off > 0; off >>= 1) pr += __shfl_down(pr, off, 64);
    if (f == 0) out[b] = 1.f / (1.f + __expf(-(pr + bl3[0])));
}

extern "C" void kernel_launch(void* const* d_in, const int* in_sizes, int n_in,
                              void* d_out, int out_size, void* d_ws, size_t ws_size,
                              hipStream_t stream) {
    const float* x = (const float*)d_in[0];
    const int* ei = (const int*)d_in[1];
    const float* points = (const float*)d_in[2];
    const float* W1 = (const float*)d_in[3];
    const float* b1 = (const float*)d_in[4];
    const float* W2 = (const float*)d_in[5];
    const float* b2 = (const float*)d_in[6];
    const float* W3 = (const float*)d_in[7];
    const float* b3 = (const float*)d_in[8];
    const float* Wg1 = (const float*)d_in[9];
    const float* asrc1 = (const float*)d_in[10];
    const float* adst1 = (const float*)d_in[11];
    const float* bg1 = (const float*)d_in[12];
    const float* Wg2 = (const float*)d_in[13];
    const float* asrc2 = (const float*)d_in[14];
    const float* adst2 = (const float*)d_in[15];
    const float* bg2 = (const float*)d_in[16];
    const float* c1W = (const float*)d_in[17];
    const float* c1b = (const float*)d_in[18];
    const float* g1 = (const float*)d_in[19];
    const float* be1 = (const float*)d_in[20];
    const float* c2W = (const float*)d_in[21];
    const float* c2b = (const float*)d_in[22];
    const float* g2 = (const float*)d_in[23];
    const float* be2 = (const float*)d_in[24];
    const float* c3W = (const float*)d_in[25];
    const float* c3b = (const float*)d_in[26];
    const float* Wl2 = (const float*)d_in[27];
    const float* bl2 = (const float*)d_in[28];
    const float* Wl3 = (const float*)d_in[29];
    const float* bl3 = (const float*)d_in[30];

    const int* src = ei;
    const int* dst = ei + EE;

    // ---- workspace carve-up ----
    char* w = (char*)d_ws;
    size_t off = 0;
    auto A = [&](size_t bytes) -> void* {
        void* p = w + off;
        off = (off + bytes + 255) & ~(size_t)255;
        return p;
    };
    int* colb = (int*)A((size_t)EE * 4);
    int* rp = (int*)A((size_t)(NN + 1) * 4);
    int* gcnt = (int*)A(NBUCK * 4);
    int* bbase = (int*)A(NBUCK * 4);
    float* dinv = (float*)A((size_t)NN * 4);
    float* bufA = (float*)A((size_t)NN * 64 * 4);
    float* bufB = (float*)A((size_t)NN * 64 * 4);
    float* ew = (float*)A((size_t)EE * 4);
    float* wself = (float*)A((size_t)NN * 4);
    float* invden = (float*)A((size_t)NN * 4);
    float* es = (float*)A((size_t)NN * 4);
    float* edv = (float*)A((size_t)NN * 4);
    float* pooled = (float*)A((size_t)BB * CCROSS * 64 * 4);
    float* xw2 = (float*)A((size_t)BB * CCROSS * 64 * 4);
    float* es2 = (float*)A((size_t)BB * CCROSS * 4);
    float* ed2 = (float*)A((size_t)BB * CCROSS * 4);
    float* crosso = (float*)A((size_t)BB * CCROSS * 64 * 4);
    float* hG = (float*)A((size_t)BB * 64 * 4);
    float* partials = (float*)A((size_t)BB * 8 * 64 * 4);

    // buckets region aliases bufA (12.6 MB <= 64 MB; dead before bufA's first real use)
    unsigned* buckets = (unsigned*)bufA;

    // ---- CSR build (bucketed) ----
    hipMemsetAsync(gcnt, 0, NBUCK * 4, stream);
    bucket_a_k<<<EE / 8192, 256, 0, stream>>>(src, dst, buckets, gcnt);
    bucket_scan_k<<<1, 256, 0, stream>>>(gcnt, bbase, rp);
    bucket_b_k<<<NBUCK, 256, 0, stream>>>(buckets, gcnt, bbase, rp, dinv, colb);

    // ---- points branch ----
    conv_fused_k<<<BB * 8, 256, 0, stream>>>(points, c1W, c1b, g1, be1, c2W, c2b, g2, be2, c3W, c3b, partials);

    // ---- GCN 1/2/3 (aggregate-before-transform) ----
    zprep_k<<<NN / 256, 256, 0, stream>>>(x, dinv, bufB);                       // bufB = z1 [NN x 20]
    agg_sum_k<5><<<(NN * 5) / 256, 256, 0, stream>>>(bufB, rp, colb, bufA);     // bufA = agg(z1)
    gcn_gemm_k<19, 20, 32, 0, true><<<NN / 256, 256, 0, stream>>>(bufA, W1, dinv, b1, bufB);   // bufB = z2 [NN x 32]
    agg_sum_k<8><<<(NN * 8) / 256, 256, 0, stream>>>(bufB, rp, colb, bufA);     // bufA = agg(z2)
    gcn_gemm_k<32, 32, 64, 1, true><<<NN / 256, 256, 0, stream>>>(bufA, W2, dinv, b2, bufB);   // bufB = z3 [NN x 64]
    agg_sum_k<16><<<(NN * 16) / 256, 256, 0, stream>>>(bufB, rp, colb, bufA);   // bufA = agg(z3)
    gcn_gemm_k<64, 64, 64, 1, false><<<NN / 256, 256, 0, stream>>>(bufA, W3, dinv, b3, bufB);  // bufB = h3

    // ---- GAT 1 ----
    gat_gemm_k<64, 64><<<NN / 256, 256, 0, stream>>>(bufB, Wg1, bufA, asrc1, adst1, es, edv, NN);
    gat_w_k<<<NN / 256, 256, 0, stream>>>(es, edv, rp, colb, ew, wself, invden);
    gat_agg_k<<<(NN * 16) / 256, 256, 0, stream>>>(bufA, rp, colb, ew, wself, invden, bg1, bufB);

    // ---- pool pieces -> cross GAT -> pool cross ----
    pool_pieces_k<<<(BB * CCROSS * 64) / 256, 256, 0, stream>>>(bufB, pooled);
    gat_gemm_k<64, 64><<<(BB * CCROSS) / 256, 256, 0, stream>>>(pooled, Wg2, xw2, asrc2, adst2, es2, ed2, BB * CCROSS);
    cross_att_k<<<(BB * CCROSS * 64) / 256, 256, 0, stream>>>(xw2, es2, ed2, bg2, crosso);
    pool_cross_k<<<BB, 64, 0, stream>>>(crosso, hG);

    // ---- head ----
    head_k<<<BB, 64, 0, stream>>>(hG, partials, Wl2, bl2, Wl3, bl3, (float*)d_out);
}

// Round 5
// 700.900 us; speedup vs baseline: 3.2015x; 1.1384x over previous
//
#include <hip/hip_runtime.h>
#include <cstdint>
#include <cstddef>

#define NN 262144
#define EE 2097152
#define BB 64
#define CCROSS 32
#define PCC 128
#define PP 2048
#define NBUCK 256
#define BCAP 12288

typedef _Float16 f16;
typedef __attribute__((ext_vector_type(4))) _Float16 f16x4;

static __device__ __forceinline__ float lrelu(float x, float s) { return x > 0.f ? x : s * x; }

// ---------------- bucketed CSR build ----------------
__global__ __launch_bounds__(256) void bucket_a_k(const int* __restrict__ src, const int* __restrict__ dst,
                                                  unsigned* __restrict__ buckets, int* __restrict__ gcnt) {
    __shared__ int hist[NBUCK];
    __shared__ int base[NBUCK];
    __shared__ unsigned short rankbuf[8192];
    const int tid = threadIdx.x;
    const int e0 = blockIdx.x * 8192;
    hist[tid] = 0;
    __syncthreads();
    for (int i = tid; i < 8192; i += 256) {
        int d = dst[e0 + i];
        rankbuf[i] = (unsigned short)atomicAdd(&hist[d >> 10], 1);
    }
    __syncthreads();
    base[tid] = tid * BCAP + atomicAdd(&gcnt[tid], hist[tid]);
    __syncthreads();
    for (int i = tid; i < 8192; i += 256) {
        int s = src[e0 + i];
        int d = dst[e0 + i];
        int b = d >> 10;
        buckets[base[b] + rankbuf[i]] = ((unsigned)s << 10) | (unsigned)(d & 1023);
    }
}

__global__ void bucket_scan_k(const int* __restrict__ gcnt, int* __restrict__ bbase, int* __restrict__ rp) {
    __shared__ int tmp[256];
    int tid = threadIdx.x;
    int v = gcnt[tid];
    tmp[tid] = v;
    __syncthreads();
    for (int off = 1; off < 256; off <<= 1) {
        int t = (tid >= off) ? tmp[tid - off] : 0;
        __syncthreads();
        tmp[tid] += t;
        __syncthreads();
    }
    bbase[tid] = tmp[tid] - v;
    if (tid == 0) rp[NN] = EE;
}

__global__ __launch_bounds__(256) void bucket_b_k(const unsigned* __restrict__ buckets, const int* __restrict__ gcnt,
                                                  const int* __restrict__ bbase, int* __restrict__ rp,
                                                  float* __restrict__ dinv, int* __restrict__ col) {
    __shared__ int cnt[1024];
    __shared__ int scan[1024];
    __shared__ int wsum[256];
    const int b = blockIdx.x;
    const int tid = threadIdx.x;
    int n = gcnt[b];
    if (n > BCAP) n = BCAP;
    const unsigned* eb = buckets + (size_t)b * BCAP;
    const int gb = bbase[b];
    for (int i = tid; i < 1024; i += 256) cnt[i] = 0;
    __syncthreads();
    for (int i = tid; i < n; i += 256) atomicAdd(&cnt[eb[i] & 1023], 1);
    __syncthreads();
    int b4 = tid * 4;
    int c0 = cnt[b4], c1 = cnt[b4 + 1], c2 = cnt[b4 + 2], c3 = cnt[b4 + 3];
    int tsum = c0 + c1 + c2 + c3;
    wsum[tid] = tsum;
    __syncthreads();
    for (int off = 1; off < 256; off <<= 1) {
        int t = (tid >= off) ? wsum[tid - off] : 0;
        __syncthreads();
        wsum[tid] += t;
        __syncthreads();
    }
    int excl = wsum[tid] - tsum;
    scan[b4] = excl;
    scan[b4 + 1] = excl + c0;
    scan[b4 + 2] = excl + c0 + c1;
    scan[b4 + 3] = excl + c0 + c1 + c2;
    int vbase = b * 1024 + b4;
    rp[vbase + 0] = gb + scan[b4 + 0];
    rp[vbase + 1] = gb + scan[b4 + 1];
    rp[vbase + 2] = gb + scan[b4 + 2];
    rp[vbase + 3] = gb + scan[b4 + 3];
    dinv[vbase + 0] = rsqrtf((float)(c0 + 1));
    dinv[vbase + 1] = rsqrtf((float)(c1 + 1));
    dinv[vbase + 2] = rsqrtf((float)(c2 + 1));
    dinv[vbase + 3] = rsqrtf((float)(c3 + 1));
    __syncthreads();
    for (int i = tid; i < 1024; i += 256) cnt[i] = 0;
    __syncthreads();
    for (int i = tid; i < n; i += 256) {
        unsigned p = eb[i];
        int dl = p & 1023;
        int r = atomicAdd(&cnt[dl], 1);
        col[gb + scan[dl] + r] = (int)(p >> 10);
    }
}

// ---------------- z-prep: z[v] = dinv[v]*x[v] fp16, padded 19 -> 32 halfs (64B row) ----------------
__global__ void zprep_k(const float* __restrict__ x, const float* __restrict__ dinv, f16* __restrict__ z) {
    int v = blockIdx.x * 256 + threadIdx.x;
    if (v >= NN) return;
    float dv = dinv[v];
    const float* xr = x + (size_t)v * 19;
    float vv[20];
#pragma unroll
    for (int k = 0; k < 19; k++) vv[k] = dv * xr[k];
    vv[19] = 0.f;
    f16x4* zr = (f16x4*)(z + (size_t)v * 32);
#pragma unroll
    for (int c = 0; c < 5; c++) {
        f16x4 t = {(f16)vv[4 * c], (f16)vv[4 * c + 1], (f16)vv[4 * c + 2], (f16)vv[4 * c + 3]};
        zr[c] = t;
    }
}

// ---------------- plain sum aggregation over fp16 rows ----------------
// L lanes per row, each loads one f16x4 chunk (8B); row stride S chunks; out stride 4L floats.
template <int L, int S>
__global__ __launch_bounds__(256) void agg_sum_h_k(const f16* __restrict__ y, const int* __restrict__ rp,
                                                   const int* __restrict__ col, float* __restrict__ out) {
    int gid = blockIdx.x * 256 + threadIdx.x;
    int v = gid / L;
    int idx = gid - v * L;
    if (v >= NN) return;
    const f16x4* y4 = (const f16x4*)y;
    f16x4 a = y4[(size_t)v * S + idx];  // self loop
    float accx = (float)a.x, accy = (float)a.y, accz = (float)a.z, accw = (float)a.w;
    int s = rp[v], e = rp[v + 1];
    int i = s;
    for (; i + 4 <= e; i += 4) {
        int u0 = col[i], u1 = col[i + 1], u2 = col[i + 2], u3 = col[i + 3];
        f16x4 a0 = y4[(size_t)u0 * S + idx];
        f16x4 a1 = y4[(size_t)u1 * S + idx];
        f16x4 a2 = y4[(size_t)u2 * S + idx];
        f16x4 a3 = y4[(size_t)u3 * S + idx];
        accx += ((float)a0.x + (float)a1.x) + ((float)a2.x + (float)a3.x);
        accy += ((float)a0.y + (float)a1.y) + ((float)a2.y + (float)a3.y);
        accz += ((float)a0.z + (float)a1.z) + ((float)a2.z + (float)a3.z);
        accw += ((float)a0.w + (float)a1.w) + ((float)a2.w + (float)a3.w);
    }
    for (; i < e; i++) {
        f16x4 aa = y4[(size_t)col[i] * S + idx];
        accx += (float)aa.x; accy += (float)aa.y; accz += (float)aa.z; accw += (float)aa.w;
    }
    float4 r; r.x = accx; r.y = accy; r.z = accz; r.w = accw;
    *(float4*)(out + (size_t)v * (4 * L) + 4 * idx) = r;
}

// ---------------- GCN gemm: out = act(dinv*(in@W) + b); WRITEZ -> fp16 rows pre-scaled by dinv ----------------
template <int KIN, int STRIDE, int KOUT, int ACT, bool WRITEZ>
__global__ __launch_bounds__(256) void gcn_gemm_k(const float* __restrict__ x, const float* __restrict__ W,
                                                  const float* __restrict__ dinv, const float* __restrict__ bias,
                                                  float* __restrict__ yf, f16* __restrict__ yh) {
    int v = blockIdx.x * 256 + threadIdx.x;
    if (v >= NN) return;
    const float* xr = x + (size_t)v * STRIDE;
    float acc[KOUT];
#pragma unroll
    for (int j = 0; j < KOUT; j++) acc[j] = 0.f;
#pragma unroll 2
    for (int k = 0; k < KIN; k++) {
        float xv = xr[k];
#pragma unroll
        for (int j = 0; j < KOUT; j++) acc[j] = fmaf(xv, W[k * KOUT + j], acc[j]);
    }
    float dv = dinv[v];
#pragma unroll
    for (int j4 = 0; j4 < KOUT / 4; j4++) {
        float4 t;
        t.x = dv * acc[4 * j4 + 0] + bias[4 * j4 + 0];
        t.y = dv * acc[4 * j4 + 1] + bias[4 * j4 + 1];
        t.z = dv * acc[4 * j4 + 2] + bias[4 * j4 + 2];
        t.w = dv * acc[4 * j4 + 3] + bias[4 * j4 + 3];
        if (ACT == 0) {
            t.x = fmaxf(t.x, 0.f); t.y = fmaxf(t.y, 0.f); t.z = fmaxf(t.z, 0.f); t.w = fmaxf(t.w, 0.f);
        } else {
            t.x = lrelu(t.x, 0.01f); t.y = lrelu(t.y, 0.01f); t.z = lrelu(t.z, 0.01f); t.w = lrelu(t.w, 0.01f);
        }
        if constexpr (WRITEZ) {
            f16x4 h = {(f16)(t.x * dv), (f16)(t.y * dv), (f16)(t.z * dv), (f16)(t.w * dv)};
            ((f16x4*)(yh + (size_t)v * KOUT))[j4] = h;
        } else {
            ((float4*)(yf + (size_t)v * KOUT))[j4] = t;
        }
    }
}

// ---------------- GAT input gemm (fp16 y out):  y[v] = x[v] @ W  (+ es/ed dots) ----------------
__global__ void gat_gemm_h_k(const float* __restrict__ x, const float* __restrict__ W,
                             f16* __restrict__ y, const float* __restrict__ av, const float* __restrict__ ad,
                             float* __restrict__ es, float* __restrict__ ed) {
    int v = blockIdx.x * 256 + threadIdx.x;
    if (v >= NN) return;
    const float* xr = x + (size_t)v * 64;
    float acc[64];
#pragma unroll
    for (int j = 0; j < 64; j++) acc[j] = 0.f;
#pragma unroll 2
    for (int k = 0; k < 64; k++) {
        float xv = xr[k];
#pragma unroll
        for (int j = 0; j < 64; j++) acc[j] = fmaf(xv, W[k * 64 + j], acc[j]);
    }
    float e1 = 0.f, e2 = 0.f;
    f16x4* y4 = (f16x4*)(y + (size_t)v * 64);
#pragma unroll
    for (int j4 = 0; j4 < 16; j4++) {
        float t0 = acc[4 * j4 + 0], t1 = acc[4 * j4 + 1], t2 = acc[4 * j4 + 2], t3 = acc[4 * j4 + 3];
        f16x4 h = {(f16)t0, (f16)t1, (f16)t2, (f16)t3};
        y4[j4] = h;
        e1 = fmaf(t0, av[4 * j4 + 0], e1); e1 = fmaf(t1, av[4 * j4 + 1], e1);
        e1 = fmaf(t2, av[4 * j4 + 2], e1); e1 = fmaf(t3, av[4 * j4 + 3], e1);
        e2 = fmaf(t0, ad[4 * j4 + 0], e2); e2 = fmaf(t1, ad[4 * j4 + 1], e2);
        e2 = fmaf(t2, ad[4 * j4 + 2], e2); e2 = fmaf(t3, ad[4 * j4 + 3], e2);
    }
    es[v] = e1; ed[v] = e2;
}

// ---------------- GAT input gemm (fp32 out, small cross-graph path) ----------------
template <int KIN, int KOUT>
__global__ void gat_gemm_k(const float* __restrict__ x, const float* __restrict__ W,
                           float* __restrict__ y, const float* __restrict__ av, const float* __restrict__ ad,
                           float* __restrict__ es, float* __restrict__ ed, int n) {
    int v = blockIdx.x * 256 + threadIdx.x;
    if (v >= n) return;
    const float* xr = x + (size_t)v * KIN;
    float acc[KOUT];
#pragma unroll
    for (int j = 0; j < KOUT; j++) acc[j] = 0.f;
#pragma unroll 2
    for (int k = 0; k < KIN; k++) {
        float xv = xr[k];
#pragma unroll
        for (int j = 0; j < KOUT; j++) acc[j] = fmaf(xv, W[k * KOUT + j], acc[j]);
    }
    float e1 = 0.f, e2 = 0.f;
    float4* y4 = (float4*)(y + (size_t)v * KOUT);
#pragma unroll
    for (int j4 = 0; j4 < KOUT / 4; j4++) {
        float4 t;
        t.x = acc[4 * j4 + 0]; t.y = acc[4 * j4 + 1]; t.z = acc[4 * j4 + 2]; t.w = acc[4 * j4 + 3];
        y4[j4] = t;
        e1 = fmaf(t.x, av[4 * j4 + 0], e1); e1 = fmaf(t.y, av[4 * j4 + 1], e1);
        e1 = fmaf(t.z, av[4 * j4 + 2], e1); e1 = fmaf(t.w, av[4 * j4 + 3], e1);
        e2 = fmaf(t.x, ad[4 * j4 + 0], e2); e2 = fmaf(t.y, ad[4 * j4 + 1], e2);
        e2 = fmaf(t.z, ad[4 * j4 + 2], e2); e2 = fmaf(t.w, ad[4 * j4 + 3], e2);
    }
    es[v] = e1; ed[v] = e2;
}

// ---------------- GAT edge softmax weights ----------------
__global__ void gat_w_k(const float* __restrict__ es, const float* __restrict__ ed,
                        const int* __restrict__ rp, const int* __restrict__ col,
                        float* __restrict__ ew, float* __restrict__ wself, float* __restrict__ invden) {
    int v = blockIdx.x * 256 + threadIdx.x;
    if (v >= NN) return;
    float edv = ed[v];
    float eself = lrelu(es[v] + edv, 0.2f);
    float m = eself;
    int s = rp[v], e = rp[v + 1];
    int i = s;
    for (; i + 4 <= e; i += 4) {
        int u0 = col[i], u1 = col[i + 1], u2 = col[i + 2], u3 = col[i + 3];
        float t0 = lrelu(es[u0] + edv, 0.2f);
        float t1 = lrelu(es[u1] + edv, 0.2f);
        float t2 = lrelu(es[u2] + edv, 0.2f);
        float t3 = lrelu(es[u3] + edv, 0.2f);
        ew[i] = t0; ew[i + 1] = t1; ew[i + 2] = t2; ew[i + 3] = t3;
        m = fmaxf(m, fmaxf(fmaxf(t0, t1), fmaxf(t2, t3)));
    }
    for (; i < e; i++) {
        float t = lrelu(es[col[i]] + edv, 0.2f);
        ew[i] = t;
        m = fmaxf(m, t);
    }
    float wsl = __expf(eself - m);
    float den = wsl;
    for (i = s; i < e; i++) {
        float w = __expf(ew[i] - m);
        ew[i] = w;
        den += w;
    }
    wself[v] = wsl;
    invden[v] = 1.f / den;
}

// ---------------- GAT aggregation over fp16 rows ----------------
__global__ __launch_bounds__(256) void gat_agg_h_k(const f16* __restrict__ y, const int* __restrict__ rp,
                                                   const int* __restrict__ col, const float* __restrict__ ew,
                                                   const float* __restrict__ wself, const float* __restrict__ invden,
                                                   const float* __restrict__ bias, float* __restrict__ out) {
    int gid = blockIdx.x * 256 + threadIdx.x;
    int v = gid >> 4;
    int idx = gid & 15;
    const f16x4* y4 = (const f16x4*)y;
    float ws = wself[v];
    f16x4 self = y4[(size_t)v * 16 + idx];
    float accx = ws * (float)self.x, accy = ws * (float)self.y, accz = ws * (float)self.z, accw = ws * (float)self.w;
    int s = rp[v], e = rp[v + 1];
    int i = s;
    for (; i + 4 <= e; i += 4) {
        int u0 = col[i], u1 = col[i + 1], u2 = col[i + 2], u3 = col[i + 3];
        float w0 = ew[i], w1 = ew[i + 1], w2 = ew[i + 2], w3 = ew[i + 3];
        f16x4 a0 = y4[(size_t)u0 * 16 + idx];
        f16x4 a1 = y4[(size_t)u1 * 16 + idx];
        f16x4 a2 = y4[(size_t)u2 * 16 + idx];
        f16x4 a3 = y4[(size_t)u3 * 16 + idx];
        accx = fmaf(w0, (float)a0.x, fmaf(w1, (float)a1.x, fmaf(w2, (float)a2.x, fmaf(w3, (float)a3.x, accx))));
        accy = fmaf(w0, (float)a0.y, fmaf(w1, (float)a1.y, fmaf(w2, (float)a2.y, fmaf(w3, (float)a3.y, accy))));
        accz = fmaf(w0, (float)a0.z, fmaf(w1, (float)a1.z, fmaf(w2, (float)a2.z, fmaf(w3, (float)a3.z, accz))));
        accw = fmaf(w0, (float)a0.w, fmaf(w1, (float)a1.w, fmaf(w2, (float)a2.w, fmaf(w3, (float)a3.w, accw))));
    }
    for (; i < e; i++) {
        float w = ew[i];
        f16x4 a = y4[(size_t)col[i] * 16 + idx];
        accx = fmaf(w, (float)a.x, accx); accy = fmaf(w, (float)a.y, accy);
        accz = fmaf(w, (float)a.z, accz); accw = fmaf(w, (float)a.w, accw);
    }
    float inv = invden[v];
    const float4* b4 = (const float4*)bias;
    float4 bb = b4[idx];
    float4 r;
    r.x = accx * inv + bb.x; r.y = accy * inv + bb.y;
    r.z = accz * inv + bb.z; r.w = accw * inv + bb.w;
    ((float4*)out)[(size_t)v * 16 + idx] = r;
}

// ---------------- pooling ----------------
__global__ void pool_pieces_k(const float* __restrict__ in, float* __restrict__ out) {
    int gid = blockIdx.x * 256 + threadIdx.x;
    if (gid >= BB * CCROSS * 64) return;
    int f = gid & 63, g = gid >> 6;
    const float* p = in + (size_t)g * PCC * 64 + f;
    float s = 0.f;
#pragma unroll 8
    for (int i = 0; i < PCC; i++) s += p[(size_t)i * 64];
    out[gid] = s * (1.f / 128.f);
}

__global__ void pool_cross_k(const float* __restrict__ in, float* __restrict__ out) {
    int gid = blockIdx.x * 64 + threadIdx.x;
    if (gid >= BB * 64) return;
    int f = gid & 63, b = gid >> 6;
    const float* p = in + (size_t)b * CCROSS * 64 + f;
    float s = 0.f;
#pragma unroll
    for (int i = 0; i < CCROSS; i++) s += p[(size_t)i * 64];
    out[gid] = s * (1.f / 32.f);
}

// ---------------- dense cross-graph GAT ----------------
__global__ void cross_att_k(const float* __restrict__ xw, const float* __restrict__ es,
                            const float* __restrict__ ed, const float* __restrict__ bg,
                            float* __restrict__ out) {
    int gid = blockIdx.x * 256 + threadIdx.x;
    if (gid >= BB * CCROSS * 64) return;
    int f = gid & 63;
    int d = (gid >> 6) & 31;
    int g = gid >> 11;
    int base = g * CCROSS;
    float edd = ed[base + d];
    float m = -1e30f;
#pragma unroll
    for (int s = 0; s < CCROSS; s++) {
        float e = lrelu(es[base + s] + edd, 0.2f);
        m = fmaxf(m, e);
    }
    float den = 0.f, acc = 0.f;
#pragma unroll
    for (int s = 0; s < CCROSS; s++) {
        float e = lrelu(es[base + s] + edd, 0.2f);
        float w = __expf(e - m) * ((s == d) ? 1.f : 2.f);
        den += w;
        acc = fmaf(w, xw[(size_t)(base + s) * 64 + f], acc);
    }
    out[gid] = acc / den + bg[f];
}

// ---------------- fused conv branch ----------------
#define S0_STR 264
#define S1_STR 132
#define S2_STR 66
#define S0_OFF 0
#define S1_OFF (3 * S0_STR)
#define S2_OFF (S1_OFF + 32 * S1_STR)
#define SMEM_FLOATS (S2_OFF + 64 * S2_STR)

__global__ __launch_bounds__(256) void conv_fused_k(
        const float* __restrict__ pts, const float* __restrict__ c1W, const float* __restrict__ c1b,
        const float* __restrict__ g1, const float* __restrict__ be1,
        const float* __restrict__ c2W, const float* __restrict__ c2b,
        const float* __restrict__ g2, const float* __restrict__ be2,
        const float* __restrict__ c3W, const float* __restrict__ c3b,
        float* __restrict__ partials) {
    __shared__ float smem[SMEM_FLOATS];
    float* s0 = smem + S0_OFF;
    float* s1 = smem + S1_OFF;
    float* s2 = smem + S2_OFF;
    float* s3 = smem;

    const int b = blockIdx.x >> 3;
    const int q = blockIdx.x & 7;
    const int tid = threadIdx.x;
    const float bnscale = 0.99999500003749968f;

    const int lo0 = 256 * q - 7;
    for (int t = tid; t < 3 * 263; t += 256) {
        int c = t / 263, j = t - c * 263;
        int p = lo0 + j;
        s0[c * S0_STR + j] = (p >= 0 && p < PP) ? pts[((size_t)b * 3 + c) * PP + p] : 0.f;
    }
    __syncthreads();

    const int lo1 = 128 * q - 3;
    for (int t = tid; t < 32 * 131; t += 256) {
        int ch = t / 131, j = t - ch * 131;
        int p1 = lo1 + j;
        float v = 0.f;
        if (p1 >= 0 && p1 < 1024) {
            float acc = c1b[ch];
            const float* w = c1W + ch * 9;
            const float* x0 = s0 + 2 * j;
#pragma unroll
            for (int ci = 0; ci < 3; ci++) {
                acc = fmaf(x0[ci * S0_STR + 0], w[ci * 3 + 0], acc);
                acc = fmaf(x0[ci * S0_STR + 1], w[ci * 3 + 1], acc);
                acc = fmaf(x0[ci * S0_STR + 2], w[ci * 3 + 2], acc);
            }
            acc = lrelu(acc, 0.01f);
            v = fmaf(acc, g1[ch] * bnscale, be1[ch]);
        }
        s1[ch * S1_STR + j] = v;
    }
    __syncthreads();

    const int lo2 = 64 * q - 1;
    for (int t = tid; t < 64 * 65; t += 256) {
        int ch = t / 65, j = t - ch * 65;
        int p2 = lo2 + j;
        float v = 0.f;
        if (p2 >= 0 && p2 < 512) {
            float acc = c2b[ch];
            const float* w = c2W + ch * 96;
            const float* x1 = s1 + 2 * j;
#pragma unroll
            for (int ci = 0; ci < 32; ci++) {
                acc = fmaf(x1[ci * S1_STR + 0], w[ci * 3 + 0], acc);
                acc = fmaf(x1[ci * S1_STR + 1], w[ci * 3 + 1], acc);
                acc = fmaf(x1[ci * S1_STR + 2], w[ci * 3 + 2], acc);
            }
            acc = lrelu(acc, 0.01f);
            v = fmaf(acc, g2[ch] * bnscale, be2[ch]);
        }
        s2[ch * S2_STR + j] = v;
    }
    __syncthreads();

    for (int t = tid; t < 64 * 32; t += 256) {
        int o = t >> 5, j = t & 31;
        float acc = c3b[o];
        const float* w = c3W + o * 192;
        const float* x2 = s2 + 2 * j;
#pragma unroll 16
        for (int ci = 0; ci < 64; ci++) {
            acc = fmaf(x2[ci * S2_STR + 0], w[ci * 3 + 0], acc);
            acc = fmaf(x2[ci * S2_STR + 1], w[ci * 3 + 1], acc);
            acc = fmaf(x2[ci * S2_STR + 2], w[ci * 3 + 2], acc);
        }
        s3[t] = lrelu(acc, 0.01f);
    }
    __syncthreads();

    if (tid < 64) {
        float s = 0.f;
#pragma unroll
        for (int j = 0; j < 32; j++) s += s3[tid * 32 + j];
        partials[((size_t)b * 8 + q) * 64 + tid] = s;
    }
}

// ---------------- head ----------------
__global__ void head_k(const float* __restrict__ hG, const float* __restrict__ partials,
                       const float* __restrict__ Wl2, const float* __restrict__ bl2,
                       const float* __restrict__ Wl3, const float* __restrict__ bl3,
                       float* __restrict__ out) {
    int b = blockIdx.x;
    int f = threadIdx.x;  // 64
    __shared__ float sh[64];
    float p = 0.f;
#pragma unroll
    for (int q = 0; q < 8; q++) p += partials[((size_t)b * 8 + q) * 64 + f];
    float h = hG[b * 64 + f] + p * (1.f / 256.f);
    sh[f] = h;
    __syncthreads();
    float acc = bl2[f];
#pragma unroll
    for (int k = 0; k < 64; k++) acc = fmaf(sh[k], Wl2[k * 64 + f], acc);
    acc = lrelu(acc, 0.01f);
    float pr = acc * Wl3[f];
#pragma unroll
    for (int off = 32; off > 0; off >>= 1) pr += __shfl_down(pr, off, 64);
    if (f == 0) out[b] = 1.f / (1.f + __expf(-(pr + bl3[0])));
}

extern "C" void kernel_launch(void* const* d_in, const int* in_sizes, int n_in,
                              void* d_out, int out_size, void* d_ws, size_t ws_size,
                              hipStream_t stream) {
    const float* x = (const float*)d_in[0];
    const int* ei = (const int*)d_in[1];
    const float* points = (const float*)d_in[2];
    const float* W1 = (const float*)d_in[3];
    const float* b1 = (const float*)d_in[4];
    const float* W2 = (const float*)d_in[5];
    const float* b2 = (const float*)d_in[6];
    const float* W3 = (const float*)d_in[7];
    const float* b3 = (const float*)d_in[8];
    const float* Wg1 = (const float*)d_in[9];
    const float* asrc1 = (const float*)d_in[10];
    const float* adst1 = (const float*)d_in[11];
    const float* bg1 = (const float*)d_in[12];
    const float* Wg2 = (const float*)d_in[13];
    const float* asrc2 = (const float*)d_in[14];
    const float* adst2 = (const float*)d_in[15];
    const float* bg2 = (const float*)d_in[16];
    const float* c1W = (const float*)d_in[17];
    const float* c1b = (const float*)d_in[18];
    const float* g1 = (const float*)d_in[19];
    const float* be1 = (const float*)d_in[20];
    const float* c2W = (const float*)d_in[21];
    const float* c2b = (const float*)d_in[22];
    const float* g2 = (const float*)d_in[23];
    const float* be2 = (const float*)d_in[24];
    const float* c3W = (const float*)d_in[25];
    const float* c3b = (const float*)d_in[26];
    const float* Wl2 = (const float*)d_in[27];
    const float* bl2 = (const float*)d_in[28];
    const float* Wl3 = (const float*)d_in[29];
    const float* bl3 = (const float*)d_in[30];

    const int* src = ei;
    const int* dst = ei + EE;

    // ---- workspace carve-up ----
    char* w = (char*)d_ws;
    size_t off = 0;
    auto A = [&](size_t bytes) -> void* {
        void* p = w + off;
        off = (off + bytes + 255) & ~(size_t)255;
        return p;
    };
    int* colb = (int*)A((size_t)EE * 4);
    int* rp = (int*)A((size_t)(NN + 1) * 4);
    int* gcnt = (int*)A(NBUCK * 4);
    int* bbase = (int*)A(NBUCK * 4);
    float* dinv = (float*)A((size_t)NN * 4);
    float* bufA = (float*)A((size_t)NN * 64 * 4);
    float* bufB = (float*)A((size_t)NN * 64 * 4);
    f16* bufH = (f16*)A((size_t)NN * 64 * 2);
    float* ew = (float*)A((size_t)EE * 4);
    float* wself = (float*)A((size_t)NN * 4);
    float* invden = (float*)A((size_t)NN * 4);
    float* es = (float*)A((size_t)NN * 4);
    float* edv = (float*)A((size_t)NN * 4);
    float* pooled = (float*)A((size_t)BB * CCROSS * 64 * 4);
    float* xw2 = (float*)A((size_t)BB * CCROSS * 64 * 4);
    float* es2 = (float*)A((size_t)BB * CCROSS * 4);
    float* ed2 = (float*)A((size_t)BB * CCROSS * 4);
    float* crosso = (float*)A((size_t)BB * CCROSS * 64 * 4);
    float* hG = (float*)A((size_t)BB * 64 * 4);
    float* partials = (float*)A((size_t)BB * 8 * 64 * 4);

    // buckets region aliases bufA (12.6 MB <= 64 MB; dead before bufA's first real use)
    unsigned* buckets = (unsigned*)bufA;

    // ---- CSR build (bucketed) ----
    hipMemsetAsync(gcnt, 0, NBUCK * 4, stream);
    bucket_a_k<<<EE / 8192, 256, 0, stream>>>(src, dst, buckets, gcnt);
    bucket_scan_k<<<1, 256, 0, stream>>>(gcnt, bbase, rp);
    bucket_b_k<<<NBUCK, 256, 0, stream>>>(buckets, gcnt, bbase, rp, dinv, colb);

    // ---- points branch ----
    conv_fused_k<<<BB * 8, 256, 0, stream>>>(points, c1W, c1b, g1, be1, c2W, c2b, g2, be2, c3W, c3b, partials);

    // ---- GCN 1/2/3 (aggregate-before-transform, fp16 gather arrays) ----
    zprep_k<<<NN / 256, 256, 0, stream>>>(x, dinv, bufH);                          // bufH = z1 [NN x 32h]
    agg_sum_h_k<5, 8><<<(NN * 5) / 256, 256, 0, stream>>>(bufH, rp, colb, bufA);   // bufA = agg(z1) [NN x 20f]
    gcn_gemm_k<19, 20, 32, 0, true><<<NN / 256, 256, 0, stream>>>(bufA, W1, dinv, b1, nullptr, bufH);  // bufH = z2 [NN x 32h]
    agg_sum_h_k<8, 8><<<(NN * 8) / 256, 256, 0, stream>>>(bufH, rp, colb, bufA);   // bufA = agg(z2) [NN x 32f]
    gcn_gemm_k<32, 32, 64, 1, true><<<NN / 256, 256, 0, stream>>>(bufA, W2, dinv, b2, nullptr, bufH);  // bufH = z3 [NN x 64h]
    agg_sum_h_k<16, 16><<<(NN * 16) / 256, 256, 0, stream>>>(bufH, rp, colb, bufA);  // bufA = agg(z3) [NN x 64f]
    gcn_gemm_k<64, 64, 64, 1, false><<<NN / 256, 256, 0, stream>>>(bufA, W3, dinv, b3, bufB, nullptr);  // bufB = h3 (fp32)

    // ---- GAT 1 ----
    gat_gemm_h_k<<<NN / 256, 256, 0, stream>>>(bufB, Wg1, bufH, asrc1, adst1, es, edv);  // bufH = xw (fp16)
    gat_w_k<<<NN / 256, 256, 0, stream>>>(es, edv, rp, colb, ew, wself, invden);
    gat_agg_h_k<<<(NN * 16) / 256, 256, 0, stream>>>(bufH, rp, colb, ew, wself, invden, bg1, bufA);  // bufA = gat out

    // ---- pool pieces -> cross GAT -> pool cross ----
    pool_pieces_k<<<(BB * CCROSS * 64) / 256, 256, 0, stream>>>(bufA, pooled);
    gat_gemm_k<64, 64><<<(BB * CCROSS) / 256, 256, 0, stream>>>(pooled, Wg2, xw2, asrc2, adst2, es2, ed2, BB * CCROSS);
    cross_att_k<<<(BB * CCROSS * 64) / 256, 256, 0, stream>>>(xw2, es2, ed2, bg2, crosso);
    pool_cross_k<<<BB, 64, 0, stream>>>(crosso, hG);

    // ---- head ----
    head_k<<<BB, 64, 0, stream>>>(hG, partials, Wl2, bl2, Wl3, bl3, (float*)d_out);
}

// Round 6
// 627.925 us; speedup vs baseline: 3.5736x; 1.1162x over previous
//
#include <hip/hip_runtime.h>
#include <cstdint>
#include <cstddef>

#define NN 262144
#define EE 2097152
#define BB 64
#define CCROSS 32
#define PCC 128
#define PP 2048
#define NBUCK 256
#define BCAP 12288

typedef _Float16 f16;
typedef __attribute__((ext_vector_type(4))) _Float16 f16x4;
typedef __attribute__((ext_vector_type(8))) _Float16 f16x8;

static __device__ __forceinline__ float lrelu(float x, float s) { return x > 0.f ? x : s * x; }

// ---------------- bucketed CSR build ----------------
__global__ __launch_bounds__(256) void bucket_a_k(const int* __restrict__ src, const int* __restrict__ dst,
                                                  unsigned* __restrict__ buckets, int* __restrict__ gcnt) {
    __shared__ int hist[NBUCK];
    __shared__ int base[NBUCK];
    __shared__ unsigned short rankbuf[8192];
    const int tid = threadIdx.x;
    const int e0 = blockIdx.x * 8192;
    hist[tid] = 0;
    __syncthreads();
    for (int i = tid; i < 8192; i += 256) {
        int d = dst[e0 + i];
        rankbuf[i] = (unsigned short)atomicAdd(&hist[d >> 10], 1);
    }
    __syncthreads();
    base[tid] = tid * BCAP + atomicAdd(&gcnt[tid], hist[tid]);
    __syncthreads();
    for (int i = tid; i < 8192; i += 256) {
        int s = src[e0 + i];
        int d = dst[e0 + i];
        int b = d >> 10;
        buckets[base[b] + rankbuf[i]] = ((unsigned)s << 10) | (unsigned)(d & 1023);
    }
}

__global__ void bucket_scan_k(const int* __restrict__ gcnt, int* __restrict__ bbase, int* __restrict__ rp) {
    __shared__ int tmp[256];
    int tid = threadIdx.x;
    int v = gcnt[tid];
    tmp[tid] = v;
    __syncthreads();
    for (int off = 1; off < 256; off <<= 1) {
        int t = (tid >= off) ? tmp[tid - off] : 0;
        __syncthreads();
        tmp[tid] += t;
        __syncthreads();
    }
    bbase[tid] = tmp[tid] - v;
    if (tid == 0) rp[NN] = EE;
}

__global__ __launch_bounds__(256) void bucket_b_k(const unsigned* __restrict__ buckets, const int* __restrict__ gcnt,
                                                  const int* __restrict__ bbase, int* __restrict__ rp,
                                                  float* __restrict__ dinv, int* __restrict__ col) {
    __shared__ int cnt[1024];
    __shared__ int scan[1024];
    __shared__ int wsum[256];
    const int b = blockIdx.x;
    const int tid = threadIdx.x;
    int n = gcnt[b];
    if (n > BCAP) n = BCAP;
    const unsigned* eb = buckets + (size_t)b * BCAP;
    const int gb = bbase[b];
    for (int i = tid; i < 1024; i += 256) cnt[i] = 0;
    __syncthreads();
    for (int i = tid; i < n; i += 256) atomicAdd(&cnt[eb[i] & 1023], 1);
    __syncthreads();
    int b4 = tid * 4;
    int c0 = cnt[b4], c1 = cnt[b4 + 1], c2 = cnt[b4 + 2], c3 = cnt[b4 + 3];
    int tsum = c0 + c1 + c2 + c3;
    wsum[tid] = tsum;
    __syncthreads();
    for (int off = 1; off < 256; off <<= 1) {
        int t = (tid >= off) ? wsum[tid - off] : 0;
        __syncthreads();
        wsum[tid] += t;
        __syncthreads();
    }
    int excl = wsum[tid] - tsum;
    scan[b4] = excl;
    scan[b4 + 1] = excl + c0;
    scan[b4 + 2] = excl + c0 + c1;
    scan[b4 + 3] = excl + c0 + c1 + c2;
    int vbase = b * 1024 + b4;
    rp[vbase + 0] = gb + scan[b4 + 0];
    rp[vbase + 1] = gb + scan[b4 + 1];
    rp[vbase + 2] = gb + scan[b4 + 2];
    rp[vbase + 3] = gb + scan[b4 + 3];
    dinv[vbase + 0] = rsqrtf((float)(c0 + 1));
    dinv[vbase + 1] = rsqrtf((float)(c1 + 1));
    dinv[vbase + 2] = rsqrtf((float)(c2 + 1));
    dinv[vbase + 3] = rsqrtf((float)(c3 + 1));
    __syncthreads();
    for (int i = tid; i < 1024; i += 256) cnt[i] = 0;
    __syncthreads();
    for (int i = tid; i < n; i += 256) {
        unsigned p = eb[i];
        int dl = p & 1023;
        int r = atomicAdd(&cnt[dl], 1);
        col[gb + scan[dl] + r] = (int)(p >> 10);
    }
}

// ---------------- z-prep: z[v] = dinv[v]*x[v] fp16, padded 19 -> 32 halfs (64B row) ----------------
__global__ void zprep_k(const float* __restrict__ x, const float* __restrict__ dinv, f16* __restrict__ z) {
    int v = blockIdx.x * 256 + threadIdx.x;
    if (v >= NN) return;
    float dv = dinv[v];
    const float* xr = x + (size_t)v * 19;
    float vv[20];
#pragma unroll
    for (int k = 0; k < 19; k++) vv[k] = dv * xr[k];
    vv[19] = 0.f;
    f16x4* zr = (f16x4*)(z + (size_t)v * 32);
#pragma unroll
    for (int c = 0; c < 5; c++) {
        f16x4 t = {(f16)vv[4 * c], (f16)vv[4 * c + 1], (f16)vv[4 * c + 2], (f16)vv[4 * c + 3]};
        zr[c] = t;
    }
}

// ---------------- plain sum aggregation over fp16 rows ----------------
template <int L, int S>
__global__ __launch_bounds__(256) void agg_sum_h_k(const f16* __restrict__ y, const int* __restrict__ rp,
                                                   const int* __restrict__ col, float* __restrict__ out) {
    int gid = blockIdx.x * 256 + threadIdx.x;
    int v = gid / L;
    int idx = gid - v * L;
    if (v >= NN) return;
    const f16x4* y4 = (const f16x4*)y;
    f16x4 a = y4[(size_t)v * S + idx];  // self loop
    float accx = (float)a.x, accy = (float)a.y, accz = (float)a.z, accw = (float)a.w;
    int s = rp[v], e = rp[v + 1];
    int i = s;
    for (; i + 4 <= e; i += 4) {
        int u0 = col[i], u1 = col[i + 1], u2 = col[i + 2], u3 = col[i + 3];
        f16x4 a0 = y4[(size_t)u0 * S + idx];
        f16x4 a1 = y4[(size_t)u1 * S + idx];
        f16x4 a2 = y4[(size_t)u2 * S + idx];
        f16x4 a3 = y4[(size_t)u3 * S + idx];
        accx += ((float)a0.x + (float)a1.x) + ((float)a2.x + (float)a3.x);
        accy += ((float)a0.y + (float)a1.y) + ((float)a2.y + (float)a3.y);
        accz += ((float)a0.z + (float)a1.z) + ((float)a2.z + (float)a3.z);
        accw += ((float)a0.w + (float)a1.w) + ((float)a2.w + (float)a3.w);
    }
    for (; i < e; i++) {
        f16x4 aa = y4[(size_t)col[i] * S + idx];
        accx += (float)aa.x; accy += (float)aa.y; accz += (float)aa.z; accw += (float)aa.w;
    }
    float4 r; r.x = accx; r.y = accy; r.z = accz; r.w = accw;
    *(float4*)(out + (size_t)v * (4 * L) + 4 * idx) = r;
}

// ---------------- LDS-staged skinny GEMM: TPR=KOUT/16 threads per row, acc = 16 floats/thread ----------------
// out = act(dinv*(x@W) + b); OMODE: 0 = fp32 out, 1 = fp16 out scaled by dinv (z for next agg), 2 = fp16 out
template <int KIN, int KSTR, int KOUT, int ACT, int OMODE>
__global__ __launch_bounds__(256) void gemm_lds_k(const float* __restrict__ x, const float* __restrict__ Wg,
                                                  const float* __restrict__ dinv, const float* __restrict__ bias,
                                                  float* __restrict__ yf, f16* __restrict__ yh) {
    constexpr int TPR = KOUT / 16;
    constexpr int RPB = 256 / TPR;
    __shared__ float Wl[KSTR * KOUT];
    const int tid = threadIdx.x;
    for (int i = tid; i < KSTR * KOUT; i += 256)
        Wl[i] = (i < KIN * KOUT) ? Wg[i] : 0.f;
    __syncthreads();
    const int row = blockIdx.x * RPB + (tid / TPR);
    const int t = tid % TPR;
    const float4* xr4 = (const float4*)(x + (size_t)row * KSTR);
    float4 a0 = {0.f, 0.f, 0.f, 0.f}, a1 = a0, a2 = a0, a3 = a0;
#pragma unroll 2
    for (int k4 = 0; k4 < KSTR / 4; k4++) {
        float4 xv = xr4[k4];
        const float* wb = Wl + (4 * k4) * KOUT + 16 * t;
#pragma unroll
        for (int kk = 0; kk < 4; kk++) {
            float xs = (kk == 0) ? xv.x : (kk == 1) ? xv.y : (kk == 2) ? xv.z : xv.w;
            const float4* wr = (const float4*)(wb + kk * KOUT);
            float4 w0 = wr[0], w1 = wr[1], w2 = wr[2], w3 = wr[3];
            a0.x = fmaf(xs, w0.x, a0.x); a0.y = fmaf(xs, w0.y, a0.y); a0.z = fmaf(xs, w0.z, a0.z); a0.w = fmaf(xs, w0.w, a0.w);
            a1.x = fmaf(xs, w1.x, a1.x); a1.y = fmaf(xs, w1.y, a1.y); a1.z = fmaf(xs, w1.z, a1.z); a1.w = fmaf(xs, w1.w, a1.w);
            a2.x = fmaf(xs, w2.x, a2.x); a2.y = fmaf(xs, w2.y, a2.y); a2.z = fmaf(xs, w2.z, a2.z); a2.w = fmaf(xs, w2.w, a2.w);
            a3.x = fmaf(xs, w3.x, a3.x); a3.y = fmaf(xs, w3.y, a3.y); a3.z = fmaf(xs, w3.z, a3.z); a3.w = fmaf(xs, w3.w, a3.w);
        }
    }
    float dv = dinv[row];
    const float4* bb = (const float4*)(bias + 16 * t);
    float4 b0 = bb[0], b1 = bb[1], b2 = bb[2], b3 = bb[3];
    a0.x = dv * a0.x + b0.x; a0.y = dv * a0.y + b0.y; a0.z = dv * a0.z + b0.z; a0.w = dv * a0.w + b0.w;
    a1.x = dv * a1.x + b1.x; a1.y = dv * a1.y + b1.y; a1.z = dv * a1.z + b1.z; a1.w = dv * a1.w + b1.w;
    a2.x = dv * a2.x + b2.x; a2.y = dv * a2.y + b2.y; a2.z = dv * a2.z + b2.z; a2.w = dv * a2.w + b2.w;
    a3.x = dv * a3.x + b3.x; a3.y = dv * a3.y + b3.y; a3.z = dv * a3.z + b3.z; a3.w = dv * a3.w + b3.w;
    if (ACT == 0) {
        a0.x = fmaxf(a0.x, 0.f); a0.y = fmaxf(a0.y, 0.f); a0.z = fmaxf(a0.z, 0.f); a0.w = fmaxf(a0.w, 0.f);
        a1.x = fmaxf(a1.x, 0.f); a1.y = fmaxf(a1.y, 0.f); a1.z = fmaxf(a1.z, 0.f); a1.w = fmaxf(a1.w, 0.f);
        a2.x = fmaxf(a2.x, 0.f); a2.y = fmaxf(a2.y, 0.f); a2.z = fmaxf(a2.z, 0.f); a2.w = fmaxf(a2.w, 0.f);
        a3.x = fmaxf(a3.x, 0.f); a3.y = fmaxf(a3.y, 0.f); a3.z = fmaxf(a3.z, 0.f); a3.w = fmaxf(a3.w, 0.f);
    } else {
        a0.x = lrelu(a0.x, 0.01f); a0.y = lrelu(a0.y, 0.01f); a0.z = lrelu(a0.z, 0.01f); a0.w = lrelu(a0.w, 0.01f);
        a1.x = lrelu(a1.x, 0.01f); a1.y = lrelu(a1.y, 0.01f); a1.z = lrelu(a1.z, 0.01f); a1.w = lrelu(a1.w, 0.01f);
        a2.x = lrelu(a2.x, 0.01f); a2.y = lrelu(a2.y, 0.01f); a2.z = lrelu(a2.z, 0.01f); a2.w = lrelu(a2.w, 0.01f);
        a3.x = lrelu(a3.x, 0.01f); a3.y = lrelu(a3.y, 0.01f); a3.z = lrelu(a3.z, 0.01f); a3.w = lrelu(a3.w, 0.01f);
    }
    if constexpr (OMODE == 0) {
        float4* yo = (float4*)(yf + (size_t)row * KOUT + 16 * t);
        yo[0] = a0; yo[1] = a1; yo[2] = a2; yo[3] = a3;
    } else {
        float s = (OMODE == 1) ? dv : 1.f;
        f16x8 h0 = {(f16)(a0.x * s), (f16)(a0.y * s), (f16)(a0.z * s), (f16)(a0.w * s),
                    (f16)(a1.x * s), (f16)(a1.y * s), (f16)(a1.z * s), (f16)(a1.w * s)};
        f16x8 h1 = {(f16)(a2.x * s), (f16)(a2.y * s), (f16)(a2.z * s), (f16)(a2.w * s),
                    (f16)(a3.x * s), (f16)(a3.y * s), (f16)(a3.z * s), (f16)(a3.w * s)};
        f16x8* yo = (f16x8*)(yh + (size_t)row * KOUT + 16 * t);
        yo[0] = h0; yo[1] = h1;
    }
}

// ---------------- LDS-staged GAT gemm (fp16 in, fp16 out, es/ed dots) ----------------
__global__ __launch_bounds__(256) void gat_gemm_lds_h_k(const f16* __restrict__ x, const float* __restrict__ Wg,
                                                        const float* __restrict__ av, const float* __restrict__ ad,
                                                        f16* __restrict__ y, float* __restrict__ es, float* __restrict__ ed) {
    __shared__ float Wl[64 * 64];
    const int tid = threadIdx.x;
    for (int i = tid; i < 4096; i += 256) Wl[i] = Wg[i];
    __syncthreads();
    const int row = blockIdx.x * 64 + (tid >> 2);
    const int t = tid & 3;
    const f16x4* xr = (const f16x4*)(x + (size_t)row * 64);
    float4 a0 = {0.f, 0.f, 0.f, 0.f}, a1 = a0, a2 = a0, a3 = a0;
#pragma unroll 2
    for (int k4 = 0; k4 < 16; k4++) {
        f16x4 xh = xr[k4];
        const float* wb = Wl + (4 * k4) * 64 + 16 * t;
#pragma unroll
        for (int kk = 0; kk < 4; kk++) {
            float xs = (kk == 0) ? (float)xh.x : (kk == 1) ? (float)xh.y : (kk == 2) ? (float)xh.z : (float)xh.w;
            const float4* wr = (const float4*)(wb + kk * 64);
            float4 w0 = wr[0], w1 = wr[1], w2 = wr[2], w3 = wr[3];
            a0.x = fmaf(xs, w0.x, a0.x); a0.y = fmaf(xs, w0.y, a0.y); a0.z = fmaf(xs, w0.z, a0.z); a0.w = fmaf(xs, w0.w, a0.w);
            a1.x = fmaf(xs, w1.x, a1.x); a1.y = fmaf(xs, w1.y, a1.y); a1.z = fmaf(xs, w1.z, a1.z); a1.w = fmaf(xs, w1.w, a1.w);
            a2.x = fmaf(xs, w2.x, a2.x); a2.y = fmaf(xs, w2.y, a2.y); a2.z = fmaf(xs, w2.z, a2.z); a2.w = fmaf(xs, w2.w, a2.w);
            a3.x = fmaf(xs, w3.x, a3.x); a3.y = fmaf(xs, w3.y, a3.y); a3.z = fmaf(xs, w3.z, a3.z); a3.w = fmaf(xs, w3.w, a3.w);
        }
    }
    const float4* av4 = (const float4*)(av + 16 * t);
    const float4* ad4 = (const float4*)(ad + 16 * t);
    float4 v0 = av4[0], v1 = av4[1], v2 = av4[2], v3 = av4[3];
    float4 d0 = ad4[0], d1 = ad4[1], d2 = ad4[2], d3 = ad4[3];
    float e1 = a0.x * v0.x + a0.y * v0.y + a0.z * v0.z + a0.w * v0.w
             + a1.x * v1.x + a1.y * v1.y + a1.z * v1.z + a1.w * v1.w
             + a2.x * v2.x + a2.y * v2.y + a2.z * v2.z + a2.w * v2.w
             + a3.x * v3.x + a3.y * v3.y + a3.z * v3.z + a3.w * v3.w;
    float e2 = a0.x * d0.x + a0.y * d0.y + a0.z * d0.z + a0.w * d0.w
             + a1.x * d1.x + a1.y * d1.y + a1.z * d1.z + a1.w * d1.w
             + a2.x * d2.x + a2.y * d2.y + a2.z * d2.z + a2.w * d2.w
             + a3.x * d3.x + a3.y * d3.y + a3.z * d3.z + a3.w * d3.w;
    e1 += __shfl_xor(e1, 1); e1 += __shfl_xor(e1, 2);
    e2 += __shfl_xor(e2, 1); e2 += __shfl_xor(e2, 2);
    if (t == 0) { es[row] = e1; ed[row] = e2; }
    f16x8 h0 = {(f16)a0.x, (f16)a0.y, (f16)a0.z, (f16)a0.w, (f16)a1.x, (f16)a1.y, (f16)a1.z, (f16)a1.w};
    f16x8 h1 = {(f16)a2.x, (f16)a2.y, (f16)a2.z, (f16)a2.w, (f16)a3.x, (f16)a3.y, (f16)a3.z, (f16)a3.w};
    f16x8* yo = (f16x8*)(y + (size_t)row * 64 + 16 * t);
    yo[0] = h0; yo[1] = h1;
}

// ---------------- GAT input gemm (fp32, small cross-graph path) ----------------
template <int KIN, int KOUT>
__global__ void gat_gemm_k(const float* __restrict__ x, const float* __restrict__ W,
                           float* __restrict__ y, const float* __restrict__ av, const float* __restrict__ ad,
                           float* __restrict__ es, float* __restrict__ ed, int n) {
    int v = blockIdx.x * 256 + threadIdx.x;
    if (v >= n) return;
    const float* xr = x + (size_t)v * KIN;
    float acc[KOUT];
#pragma unroll
    for (int j = 0; j < KOUT; j++) acc[j] = 0.f;
#pragma unroll 2
    for (int k = 0; k < KIN; k++) {
        float xv = xr[k];
#pragma unroll
        for (int j = 0; j < KOUT; j++) acc[j] = fmaf(xv, W[k * KOUT + j], acc[j]);
    }
    float e1 = 0.f, e2 = 0.f;
    float4* y4 = (float4*)(y + (size_t)v * KOUT);
#pragma unroll
    for (int j4 = 0; j4 < KOUT / 4; j4++) {
        float4 t;
        t.x = acc[4 * j4 + 0]; t.y = acc[4 * j4 + 1]; t.z = acc[4 * j4 + 2]; t.w = acc[4 * j4 + 3];
        y4[j4] = t;
        e1 = fmaf(t.x, av[4 * j4 + 0], e1); e1 = fmaf(t.y, av[4 * j4 + 1], e1);
        e1 = fmaf(t.z, av[4 * j4 + 2], e1); e1 = fmaf(t.w, av[4 * j4 + 3], e1);
        e2 = fmaf(t.x, ad[4 * j4 + 0], e2); e2 = fmaf(t.y, ad[4 * j4 + 1], e2);
        e2 = fmaf(t.z, ad[4 * j4 + 2], e2); e2 = fmaf(t.w, ad[4 * j4 + 3], e2);
    }
    es[v] = e1; ed[v] = e2;
}

// ---------------- GAT edge softmax weights ----------------
__global__ void gat_w_k(const float* __restrict__ es, const float* __restrict__ ed,
                        const int* __restrict__ rp, const int* __restrict__ col,
                        float* __restrict__ ew, float* __restrict__ wself, float* __restrict__ invden) {
    int v = blockIdx.x * 256 + threadIdx.x;
    if (v >= NN) return;
    float edv = ed[v];
    float eself = lrelu(es[v] + edv, 0.2f);
    float m = eself;
    int s = rp[v], e = rp[v + 1];
    int i = s;
    for (; i + 4 <= e; i += 4) {
        int u0 = col[i], u1 = col[i + 1], u2 = col[i + 2], u3 = col[i + 3];
        float t0 = lrelu(es[u0] + edv, 0.2f);
        float t1 = lrelu(es[u1] + edv, 0.2f);
        float t2 = lrelu(es[u2] + edv, 0.2f);
        float t3 = lrelu(es[u3] + edv, 0.2f);
        ew[i] = t0; ew[i + 1] = t1; ew[i + 2] = t2; ew[i + 3] = t3;
        m = fmaxf(m, fmaxf(fmaxf(t0, t1), fmaxf(t2, t3)));
    }
    for (; i < e; i++) {
        float t = lrelu(es[col[i]] + edv, 0.2f);
        ew[i] = t;
        m = fmaxf(m, t);
    }
    float wsl = __expf(eself - m);
    float den = wsl;
    for (i = s; i < e; i++) {
        float w = __expf(ew[i] - m);
        ew[i] = w;
        den += w;
    }
    wself[v] = wsl;
    invden[v] = 1.f / den;
}

// ---------------- GAT aggregation over fp16 rows ----------------
__global__ __launch_bounds__(256) void gat_agg_h_k(const f16* __restrict__ y, const int* __restrict__ rp,
                                                   const int* __restrict__ col, const float* __restrict__ ew,
                                                   const float* __restrict__ wself, const float* __restrict__ invden,
                                                   const float* __restrict__ bias, float* __restrict__ out) {
    int gid = blockIdx.x * 256 + threadIdx.x;
    int v = gid >> 4;
    int idx = gid & 15;
    const f16x4* y4 = (const f16x4*)y;
    float ws = wself[v];
    f16x4 self = y4[(size_t)v * 16 + idx];
    float accx = ws * (float)self.x, accy = ws * (float)self.y, accz = ws * (float)self.z, accw = ws * (float)self.w;
    int s = rp[v], e = rp[v + 1];
    int i = s;
    for (; i + 4 <= e; i += 4) {
        int u0 = col[i], u1 = col[i + 1], u2 = col[i + 2], u3 = col[i + 3];
        float w0 = ew[i], w1 = ew[i + 1], w2 = ew[i + 2], w3 = ew[i + 3];
        f16x4 a0 = y4[(size_t)u0 * 16 + idx];
        f16x4 a1 = y4[(size_t)u1 * 16 + idx];
        f16x4 a2 = y4[(size_t)u2 * 16 + idx];
        f16x4 a3 = y4[(size_t)u3 * 16 + idx];
        accx = fmaf(w0, (float)a0.x, fmaf(w1, (float)a1.x, fmaf(w2, (float)a2.x, fmaf(w3, (float)a3.x, accx))));
        accy = fmaf(w0, (float)a0.y, fmaf(w1, (float)a1.y, fmaf(w2, (float)a2.y, fmaf(w3, (float)a3.y, accy))));
        accz = fmaf(w0, (float)a0.z, fmaf(w1, (float)a1.z, fmaf(w2, (float)a2.z, fmaf(w3, (float)a3.z, accz))));
        accw = fmaf(w0, (float)a0.w, fmaf(w1, (float)a1.w, fmaf(w2, (float)a2.w, fmaf(w3, (float)a3.w, accw))));
    }
    for (; i < e; i++) {
        float w = ew[i];
        f16x4 a = y4[(size_t)col[i] * 16 + idx];
        accx = fmaf(w, (float)a.x, accx); accy = fmaf(w, (float)a.y, accy);
        accz = fmaf(w, (float)a.z, accz); accw = fmaf(w, (float)a.w, accw);
    }
    float inv = invden[v];
    const float4* b4 = (const float4*)bias;
    float4 bb = b4[idx];
    float4 r;
    r.x = accx * inv + bb.x; r.y = accy * inv + bb.y;
    r.z = accz * inv + bb.z; r.w = accw * inv + bb.w;
    ((float4*)out)[(size_t)v * 16 + idx] = r;
}

// ---------------- pooling ----------------
__global__ void pool_pieces_k(const float* __restrict__ in, float* __restrict__ out) {
    int gid = blockIdx.x * 256 + threadIdx.x;
    if (gid >= BB * CCROSS * 64) return;
    int f = gid & 63, g = gid >> 6;
    const float* p = in + (size_t)g * PCC * 64 + f;
    float s = 0.f;
#pragma unroll 8
    for (int i = 0; i < PCC; i++) s += p[(size_t)i * 64];
    out[gid] = s * (1.f / 128.f);
}

__global__ void pool_cross_k(const float* __restrict__ in, float* __restrict__ out) {
    int gid = blockIdx.x * 64 + threadIdx.x;
    if (gid >= BB * 64) return;
    int f = gid & 63, b = gid >> 6;
    const float* p = in + (size_t)b * CCROSS * 64 + f;
    float s = 0.f;
#pragma unroll
    for (int i = 0; i < CCROSS; i++) s += p[(size_t)i * 64];
    out[gid] = s * (1.f / 32.f);
}

// ---------------- dense cross-graph GAT ----------------
__global__ void cross_att_k(const float* __restrict__ xw, const float* __restrict__ es,
                            const float* __restrict__ ed, const float* __restrict__ bg,
                            float* __restrict__ out) {
    int gid = blockIdx.x * 256 + threadIdx.x;
    if (gid >= BB * CCROSS * 64) return;
    int f = gid & 63;
    int d = (gid >> 6) & 31;
    int g = gid >> 11;
    int base = g * CCROSS;
    float edd = ed[base + d];
    float m = -1e30f;
#pragma unroll
    for (int s = 0; s < CCROSS; s++) {
        float e = lrelu(es[base + s] + edd, 0.2f);
        m = fmaxf(m, e);
    }
    float den = 0.f, acc = 0.f;
#pragma unroll
    for (int s = 0; s < CCROSS; s++) {
        float e = lrelu(es[base + s] + edd, 0.2f);
        float w = __expf(e - m) * ((s == d) ? 1.f : 2.f);
        den += w;
        acc = fmaf(w, xw[(size_t)(base + s) * 64 + f], acc);
    }
    out[gid] = acc / den + bg[f];
}

// ---------------- fused conv branch ----------------
#define S0_STR 264
#define S1_STR 132
#define S2_STR 66
#define S0_OFF 0
#define S1_OFF (3 * S0_STR)
#define S2_OFF (S1_OFF + 32 * S1_STR)
#define SMEM_FLOATS (S2_OFF + 64 * S2_STR)

__global__ __launch_bounds__(256) void conv_fused_k(
        const float* __restrict__ pts, const float* __restrict__ c1W, const float* __restrict__ c1b,
        const float* __restrict__ g1, const float* __restrict__ be1,
        const float* __restrict__ c2W, const float* __restrict__ c2b,
        const float* __restrict__ g2, const float* __restrict__ be2,
        const float* __restrict__ c3W, const float* __restrict__ c3b,
        float* __restrict__ partials) {
    __shared__ float smem[SMEM_FLOATS];
    float* s0 = smem + S0_OFF;
    float* s1 = smem + S1_OFF;
    float* s2 = smem + S2_OFF;
    float* s3 = smem;

    const int b = blockIdx.x >> 3;
    const int q = blockIdx.x & 7;
    const int tid = threadIdx.x;
    const float bnscale = 0.99999500003749968f;

    const int lo0 = 256 * q - 7;
    for (int t = tid; t < 3 * 263; t += 256) {
        int c = t / 263, j = t - c * 263;
        int p = lo0 + j;
        s0[c * S0_STR + j] = (p >= 0 && p < PP) ? pts[((size_t)b * 3 + c) * PP + p] : 0.f;
    }
    __syncthreads();

    const int lo1 = 128 * q - 3;
    for (int t = tid; t < 32 * 131; t += 256) {
        int ch = t / 131, j = t - ch * 131;
        int p1 = lo1 + j;
        float v = 0.f;
        if (p1 >= 0 && p1 < 1024) {
            float acc = c1b[ch];
            const float* w = c1W + ch * 9;
            const float* x0 = s0 + 2 * j;
#pragma unroll
            for (int ci = 0; ci < 3; ci++) {
                acc = fmaf(x0[ci * S0_STR + 0], w[ci * 3 + 0], acc);
                acc = fmaf(x0[ci * S0_STR + 1], w[ci * 3 + 1], acc);
                acc = fmaf(x0[ci * S0_STR + 2], w[ci * 3 + 2], acc);
            }
            acc = lrelu(acc, 0.01f);
            v = fmaf(acc, g1[ch] * bnscale, be1[ch]);
        }
        s1[ch * S1_STR + j] = v;
    }
    __syncthreads();

    const int lo2 = 64 * q - 1;
    for (int t = tid; t < 64 * 65; t += 256) {
        int ch = t / 65, j = t - ch * 65;
        int p2 = lo2 + j;
        float v = 0.f;
        if (p2 >= 0 && p2 < 512) {
            float acc = c2b[ch];
            const float* w = c2W + ch * 96;
            const float* x1 = s1 + 2 * j;
#pragma unroll
            for (int ci = 0; ci < 32; ci++) {
                acc = fmaf(x1[ci * S1_STR + 0], w[ci * 3 + 0], acc);
                acc = fmaf(x1[ci * S1_STR + 1], w[ci * 3 + 1], acc);
                acc = fmaf(x1[ci * S1_STR + 2], w[ci * 3 + 2], acc);
            }
            acc = lrelu(acc, 0.01f);
            v = fmaf(acc, g2[ch] * bnscale, be2[ch]);
        }
        s2[ch * S2_STR + j] = v;
    }
    __syncthreads();

    for (int t = tid; t < 64 * 32; t += 256) {
        int o = t >> 5, j = t & 31;
        float acc = c3b[o];
        const float* w = c3W + o * 192;
        const float* x2 = s2 + 2 * j;
#pragma unroll 16
        for (int ci = 0; ci < 64; ci++) {
            acc = fmaf(x2[ci * S2_STR + 0], w[ci * 3 + 0], acc);
            acc = fmaf(x2[ci * S2_STR + 1], w[ci * 3 + 1], acc);
            acc = fmaf(x2[ci * S2_STR + 2], w[ci * 3 + 2], acc);
        }
        s3[t] = lrelu(acc, 0.01f);
    }
    __syncthreads();

    if (tid < 64) {
        float s = 0.f;
#pragma unroll
        for (int j = 0; j < 32; j++) s += s3[tid * 32 + j];
        partials[((size_t)b * 8 + q) * 64 + tid] = s;
    }
}

// ---------------- head ----------------
__global__ void head_k(const float* __restrict__ hG, const float* __restrict__ partials,
                       const float* __restrict__ Wl2, const float* __restrict__ bl2,
                       const float* __restrict__ Wl3, const float* __restrict__ bl3,
                       float* __restrict__ out) {
    int b = blockIdx.x;
    int f = threadIdx.x;  // 64
    __shared__ float sh[64];
    float p = 0.f;
#pragma unroll
    for (int q = 0; q < 8; q++) p += partials[((size_t)b * 8 + q) * 64 + f];
    float h = hG[b * 64 + f] + p * (1.f / 256.f);
    sh[f] = h;
    __syncthreads();
    float acc = bl2[f];
#pragma unroll
    for (int k = 0; k < 64; k++) acc = fmaf(sh[k], Wl2[k * 64 + f], acc);
    acc = lrelu(acc, 0.01f);
    float pr = acc * Wl3[f];
#pragma unroll
    for (int off = 32; off > 0; off >>= 1) pr += __shfl_down(pr, off, 64);
    if (f == 0) out[b] = 1.f / (1.f + __expf(-(pr + bl3[0])));
}

extern "C" void kernel_launch(void* const* d_in, const int* in_sizes, int n_in,
                              void* d_out, int out_size, void* d_ws, size_t ws_size,
                              hipStream_t stream) {
    const float* x = (const float*)d_in[0];
    const int* ei = (const int*)d_in[1];
    const float* points = (const float*)d_in[2];
    const float* W1 = (const float*)d_in[3];
    const float* b1 = (const float*)d_in[4];
    const float* W2 = (const float*)d_in[5];
    const float* b2 = (const float*)d_in[6];
    const float* W3 = (const float*)d_in[7];
    const float* b3 = (const float*)d_in[8];
    const float* Wg1 = (const float*)d_in[9];
    const float* asrc1 = (const float*)d_in[10];
    const float* adst1 = (const float*)d_in[11];
    const float* bg1 = (const float*)d_in[12];
    const float* Wg2 = (const float*)d_in[13];
    const float* asrc2 = (const float*)d_in[14];
    const float* adst2 = (const float*)d_in[15];
    const float* bg2 = (const float*)d_in[16];
    const float* c1W = (const float*)d_in[17];
    const float* c1b = (const float*)d_in[18];
    const float* g1 = (const float*)d_in[19];
    const float* be1 = (const float*)d_in[20];
    const float* c2W = (const float*)d_in[21];
    const float* c2b = (const float*)d_in[22];
    const float* g2 = (const float*)d_in[23];
    const float* be2 = (const float*)d_in[24];
    const float* c3W = (const float*)d_in[25];
    const float* c3b = (const float*)d_in[26];
    const float* Wl2 = (const float*)d_in[27];
    const float* bl2 = (const float*)d_in[28];
    const float* Wl3 = (const float*)d_in[29];
    const float* bl3 = (const float*)d_in[30];

    const int* src = ei;
    const int* dst = ei + EE;

    // ---- workspace carve-up ----
    char* w = (char*)d_ws;
    size_t off = 0;
    auto A = [&](size_t bytes) -> void* {
        void* p = w + off;
        off = (off + bytes + 255) & ~(size_t)255;
        return p;
    };
    int* colb = (int*)A((size_t)EE * 4);
    int* rp = (int*)A((size_t)(NN + 1) * 4);
    int* gcnt = (int*)A(NBUCK * 4);
    int* bbase = (int*)A(NBUCK * 4);
    float* dinv = (float*)A((size_t)NN * 4);
    float* bufA = (float*)A((size_t)NN * 64 * 4);
    float* bufB = (float*)A((size_t)NN * 64 * 4);
    f16* bufH = (f16*)A((size_t)NN * 64 * 2);
    float* ew = (float*)A((size_t)EE * 4);
    float* wself = (float*)A((size_t)NN * 4);
    float* invden = (float*)A((size_t)NN * 4);
    float* es = (float*)A((size_t)NN * 4);
    float* edv = (float*)A((size_t)NN * 4);
    float* pooled = (float*)A((size_t)BB * CCROSS * 64 * 4);
    float* xw2 = (float*)A((size_t)BB * CCROSS * 64 * 4);
    float* es2 = (float*)A((size_t)BB * CCROSS * 4);
    float* ed2 = (float*)A((size_t)BB * CCROSS * 4);
    float* crosso = (float*)A((size_t)BB * CCROSS * 64 * 4);
    float* hG = (float*)A((size_t)BB * 64 * 4);
    float* partials = (float*)A((size_t)BB * 8 * 64 * 4);

    unsigned* buckets = (unsigned*)bufA;   // aliases bufA, dead before first real use
    f16* h3 = (f16*)bufB;                  // h3 fp16 lives in bufB region

    // ---- CSR build (bucketed) ----
    hipMemsetAsync(gcnt, 0, NBUCK * 4, stream);
    bucket_a_k<<<EE / 8192, 256, 0, stream>>>(src, dst, buckets, gcnt);
    bucket_scan_k<<<1, 256, 0, stream>>>(gcnt, bbase, rp);
    bucket_b_k<<<NBUCK, 256, 0, stream>>>(buckets, gcnt, bbase, rp, dinv, colb);

    // ---- points branch ----
    conv_fused_k<<<BB * 8, 256, 0, stream>>>(points, c1W, c1b, g1, be1, c2W, c2b, g2, be2, c3W, c3b, partials);

    // ---- GCN 1/2/3 (aggregate-before-transform, fp16 gather arrays, LDS-staged gemms) ----
    zprep_k<<<NN / 256, 256, 0, stream>>>(x, dinv, bufH);                          // bufH = z1 [NN x 32h]
    agg_sum_h_k<5, 8><<<(NN * 5) / 256, 256, 0, stream>>>(bufH, rp, colb, bufA);   // bufA = agg(z1) [NN x 20f]
    gemm_lds_k<19, 20, 32, 0, 1><<<NN / 128, 256, 0, stream>>>(bufA, W1, dinv, b1, nullptr, bufH);  // bufH = z2 [NN x 32h]
    agg_sum_h_k<8, 8><<<(NN * 8) / 256, 256, 0, stream>>>(bufH, rp, colb, bufA);   // bufA = agg(z2) [NN x 32f]
    gemm_lds_k<32, 32, 64, 1, 1><<<NN / 64, 256, 0, stream>>>(bufA, W2, dinv, b2, nullptr, bufH);   // bufH = z3 [NN x 64h]
    agg_sum_h_k<16, 16><<<(NN * 16) / 256, 256, 0, stream>>>(bufH, rp, colb, bufA);  // bufA = agg(z3) [NN x 64f]
    gemm_lds_k<64, 64, 64, 1, 2><<<NN / 64, 256, 0, stream>>>(bufA, W3, dinv, b3, nullptr, h3);     // h3 (fp16)

    // ---- GAT 1 ----
    gat_gemm_lds_h_k<<<NN / 64, 256, 0, stream>>>(h3, Wg1, asrc1, adst1, bufH, es, edv);  // bufH = xw (fp16)
    gat_w_k<<<NN / 256, 256, 0, stream>>>(es, edv, rp, colb, ew, wself, invden);
    gat_agg_h_k<<<(NN * 16) / 256, 256, 0, stream>>>(bufH, rp, colb, ew, wself, invden, bg1, bufA);  // bufA = gat out

    // ---- pool pieces -> cross GAT -> pool cross ----
    pool_pieces_k<<<(BB * CCROSS * 64) / 256, 256, 0, stream>>>(bufA, pooled);
    gat_gemm_k<64, 64><<<(BB * CCROSS) / 256, 256, 0, stream>>>(pooled, Wg2, xw2, asrc2, adst2, es2, ed2, BB * CCROSS);
    cross_att_k<<<(BB * CCROSS * 64) / 256, 256, 0, stream>>>(xw2, es2, ed2, bg2, crosso);
    pool_cross_k<<<BB, 64, 0, stream>>>(crosso, hG);

    // ---- head ----
    head_k<<<BB, 64, 0, stream>>>(hG, partials, Wl2, bl2, Wl3, bl3, (float*)d_out);
}